// Round 2
// baseline (324.955 us; speedup 1.0000x reference)
//
#include <hip/hip_runtime.h>

typedef unsigned short u16;
typedef unsigned int u32;
typedef unsigned long long u64;

#define NB 4
#define NTOK 12544
#define NBHD 48
#define DIM 256
#define OUTD 512
#define KEEPN 3136
#define SAMPLEN 2352
#define RESN 784
#define GW 112
#define TABLE 4096
#define POSN (NB * KEEPN * 2)   // 25088 floats
#define QTR (NTOK / 4)          // 3136
#define NBKT 16384

// fallback in-place GEMM tiling
#define BLKM 128
#define BLKN 256
#define BROW 40

// ws fast-path layout (bytes)
#define FEATB_BYTES (25690112ull)                 // 4*12544*256*2
#define XWS_BYTES   (25690112ull)                 // 12544*1024*2
#define LINT_BYTES  (1048576ull)                  // 512*1024*2
#define KEYS_BYTES  (401408ull)                   // slots: 4*12544*8
#define PART_BYTES  (802816ull)                   // hist+base+cursor: 786432 used
#define WS_NEED (FEATB_BYTES + XWS_BYTES + LINT_BYTES + KEYS_BYTES + PART_BYTES)

__device__ __forceinline__ float bf2f(u16 u) {
    union { u32 i; float f; } v; v.i = ((u32)u) << 16; return v.f;
}
__device__ __forceinline__ float asf(u32 u) {
    union { u32 i; float f; } v; v.i = u; return v.f;
}
__device__ __forceinline__ u16 f2bf(float f) {
    union { u32 i; float f; } v; v.f = f;
    return (u16)((v.i + 0x7FFFu + ((v.i >> 16) & 1u)) >> 16);
}

typedef __bf16 bf16x8 __attribute__((ext_vector_type(8)));
typedef float floatx4 __attribute__((ext_vector_type(4)));
typedef float floatx2 __attribute__((ext_vector_type(2)));

// final_prob, bit-exact vs reference f32 arithmetic
__device__ __forceinline__ float make_f(float lp, int n) {
    int i = n / GW, j = n % GW;
    float f = lp * 4.0f;
    if (((i | j) & 1) == 0) f = 1.0f + f;        // grid_prob (stride 2)
    if (((i | j) & 3) == 0) f = f + (-100.0f);   // reserve penalty (stride 4)
    return f;
}
// key: descending order == top_k order; ties -> lower n first
__device__ __forceinline__ u64 f_to_key(float f, int n) {
    union { float f; u32 u; } v; v.f = f;
    u32 m = (v.u & 0x80000000u) ? ~v.u : (v.u | 0x80000000u);
    return (((u64)m) << 32) | (u64)(0xFFFFFFFFu - (u32)n);
}
__device__ __forceinline__ int f_to_bucket(float f) {
    int b = (int)floorf(f * 3276.8f);            // monotone: [0,5) -> [0,16384)
    return b < 0 ? 0 : (b > NBKT - 1 ? NBKT - 1 : b);
}

// ---- convert feat f32 -> bf16 ---------------------------------------------
__global__ __launch_bounds__(256) void feat_cvt_kernel(
    const float* __restrict__ feat, u16* __restrict__ featb) {
    int t = blockIdx.x * 256 + threadIdx.x;
    float4 v = ((const float4*)feat)[t];
    u64 w = (u64)f2bf(v.x) | ((u64)f2bf(v.y) << 16) |
            ((u64)f2bf(v.z) << 32) | ((u64)f2bf(v.w) << 48);
    ((u64*)featb)[t] = w;
}

// ---- convert+transpose lin_w -> linT (512x1024 bf16); zero hist;
// ---- fused weight_net table precompute: wt[TABLE][4] = gelu(ln(pt@w1+b1))
__global__ __launch_bounds__(256) void linT_cvt_kernel(
    const float* __restrict__ lin_w, u16* __restrict__ linT,
    u32* __restrict__ hist,
    const float* __restrict__ pre_table, const float* __restrict__ w1,
    const float* __restrict__ b1, const float* __restrict__ g1,
    const float* __restrict__ bb1, float* __restrict__ wt) {
    __shared__ u16 T[64 * 65];
    int k0 = blockIdx.x * 64, n0 = blockIdx.y * 64;
    int t = threadIdx.x;
    int bid = blockIdx.y * 16 + blockIdx.x;
    // fused hist zeroing: 128 blocks x 512 entries = 65536
    hist[bid * 512 + t] = 0;
    hist[bid * 512 + 256 + t] = 0;
    // fused wt precompute: first 16 blocks cover TABLE=4096 rows
    int gid = bid * 256 + t;
    if (gid < TABLE) {
        float z[4];
#pragma unroll
        for (int m = 0; m < 4; ++m) {
            float acc = b1[m];
#pragma unroll
            for (int d = 0; d < 5; ++d) acc += pre_table[gid * 5 + d] * w1[d * 4 + m];
            z[m] = acc;
        }
        float mean = (z[0] + z[1] + z[2] + z[3]) * 0.25f;
        float var = 0.0f;
#pragma unroll
        for (int m = 0; m < 4; ++m) { float d = z[m] - mean; var += d * d; }
        float rstd = rsqrtf(var * 0.25f + 1e-5f);
        float wv[4];
#pragma unroll
        for (int m = 0; m < 4; ++m) {
            float y = (z[m] - mean) * rstd * g1[m] + bb1[m];
            wv[m] = 0.5f * y * (1.0f + erff(y * 0.70710678118654752f));
        }
        *(float4*)&wt[gid * 4] = make_float4(wv[0], wv[1], wv[2], wv[3]);
    }
    int r = t >> 2, c4 = (t & 3) * 16;
#pragma unroll
    for (int i = 0; i < 4; ++i) {
        float4 v = *(const float4*)&lin_w[(size_t)(k0 + r) * OUTD + n0 + c4 + i * 4];
        T[(c4 + i * 4 + 0) * 65 + r] = f2bf(v.x);
        T[(c4 + i * 4 + 1) * 65 + r] = f2bf(v.y);
        T[(c4 + i * 4 + 2) * 65 + r] = f2bf(v.z);
        T[(c4 + i * 4 + 3) * 65 + r] = f2bf(v.w);
    }
    __syncthreads();
    int nl = t >> 2, kc = (t & 3) * 16;
    union { uint4 v[2]; u16 h[16]; } u;
#pragma unroll
    for (int i = 0; i < 16; ++i) u.h[i] = T[nl * 65 + kc + i];
    u16* dst = &linT[(size_t)(n0 + nl) * 1024 + k0 + kc];
    *(uint4*)(dst + 0) = u.v[0];
    *(uint4*)(dst + 8) = u.v[1];
}

// ================= selection: exact counting-sort top-k =====================
__global__ __launch_bounds__(256) void hist_kernel(
    const float* __restrict__ lprob, u32* __restrict__ hist) {
    int g = blockIdx.x * 256 + threadIdx.x;        // 196 blocks
    int b = g / NTOK, n = g % NTOK;
    int bkt = f_to_bucket(make_f(lprob[g], n));
    atomicAdd(&hist[b * NBKT + bkt], 1u);
}

// descending exclusive prefix: base[e] = #keys in buckets > e
__global__ __launch_bounds__(1024) void prefix_kernel(
    const u32* __restrict__ hist, u32* __restrict__ base, u32* __restrict__ cursor) {
    int b = blockIdx.x, t = threadIdx.x;
    const u32* h = hist + b * NBKT;
    u32 loc[16], own = 0;
#pragma unroll
    for (int i = 0; i < 16; ++i) { loc[i] = h[t * 16 + i]; own += loc[i]; }
    __shared__ u32 buf[2][1024];
    buf[0][t] = own;
    __syncthreads();
    int src = 0;
    for (int off = 1; off < 1024; off <<= 1) {
        u32 v = buf[src][t] + ((t + off < 1024) ? buf[src][t + off] : 0u);
        buf[src ^ 1][t] = v;
        src ^= 1;
        __syncthreads();
    }
    u32 above = buf[src][t] - own;                 // chunks strictly after t
    u32 suf = 0, bout[16];
    for (int i = 15; i >= 0; --i) { bout[i] = above + suf; suf += loc[i]; }
    u32* bb = base + b * NBKT;
    u32* cc = cursor + b * NBKT;
#pragma unroll
    for (int i = 0; i < 16; ++i) { bb[t * 16 + i] = bout[i]; cc[t * 16 + i] = bout[i]; }
}

__global__ __launch_bounds__(256) void scatter_kernel(
    const float* __restrict__ lprob, u32* __restrict__ cursor,
    u64* __restrict__ slots) {
    int g = blockIdx.x * 256 + threadIdx.x;
    int b = g / NTOK, n = g % NTOK;
    float f = make_f(lprob[g], n);
    int bkt = f_to_bucket(f);
    u32 s = atomicAdd(&cursor[b * NBKT + bkt], 1u);
    slots[b * NTOK + s] = f_to_key(f, n);
}

__global__ __launch_bounds__(256) void rank_finalize_kernel(
    const float* __restrict__ lprob, const u32* __restrict__ hist,
    const u32* __restrict__ base, const u64* __restrict__ slots,
    float* __restrict__ pos_out) {
    int g = blockIdx.x * 256 + threadIdx.x;
    int b = g / NTOK, n = g % NTOK;
    int i = n / GW, j = n % GW;
    if (((i | j) & 3) == 0) {
        // reserve token: rank >= 11760 > SAMPLEN always; fills fixed tail slot
        int r = (i >> 2) * 28 + (j >> 2);
        int slot = b * KEEPN + SAMPLEN + r;
        pos_out[slot * 2 + 0] = (float)i;
        pos_out[slot * 2 + 1] = (float)j;
        return;
    }
    float f = make_f(lprob[g], n);
    int bkt = f_to_bucket(f);
    u32 r0 = base[b * NBKT + bkt];
    if (r0 >= SAMPLEN) return;                     // whole bucket below cut
    u64 my = f_to_key(f, n);
    u32 cnt = hist[b * NBKT + bkt];
    const u64* sl = slots + b * NTOK + r0;
    u32 rank = r0;
    for (u32 s = 0; s < cnt; ++s) rank += (sl[s] > my) ? 1u : 0u;
    if (rank < SAMPLEN) {
        int slot = b * KEEPN + (int)rank;
        pos_out[slot * 2 + 0] = (float)i;
        pos_out[slot * 2 + 1] = (float)j;
    }
}

// ---- K4 v5: split-wave dwordx4 gather + packed-f32 FMA --------------------
// Lanes 0-31 process even neighbors (16B = 8 channels each), lanes 32-63 odd.
// acc2[j][p]: channel j (of lane's 8), p=0 -> (m0,m1), p=1 -> (m2,m3).
__global__ __launch_bounds__(256) void token_v4_kernel(
    const float* __restrict__ pos_in, u16* __restrict__ xdst,
    const int* __restrict__ member_idx, const int* __restrict__ pe_idx,
    const float* __restrict__ cmask, const float* __restrict__ lprob,
    const u16* __restrict__ featb, const float* __restrict__ wt,
    const float* __restrict__ norm_g, const float* __restrict__ norm_b) {
    // XCD-affinity: block i -> xcd i&7 (round-robin dispatch);
    // batch b owns xcds {2b, 2b+1} so per-XCD hot set = 6.4 MB.
    int bi = blockIdx.x;                 // 3136 blocks, 4 tokens each
    int xcd = bi & 7, jj = bi >> 3;      // jj in [0,392)
    int b = xcd >> 1;
    int tid = threadIdx.x;
    int wave = tid >> 6, lane = tid & 63;
    int t = b * KEEPN + (xcd & 1) * 1568 + jj * 4 + wave;

    __shared__ float4 w_s[4][NBHD];
    __shared__ int moff_s[4][NBHD];      // mem*DIM (u16-element offset)

    float2 pp = *(const float2*)&pos_in[t * 2];
    int n_src = (int)pp.x * GW + (int)pp.y;

    if (lane < NBHD) {
        int e = (b * NTOK + n_src) * NBHD + lane;
        int mem = member_idx[e];
        int pe = pe_idx[e];
        float cm = cmask[e];
        float lpe = lprob[b * NTOK + mem];
        float4 w4 = *(const float4*)&wt[pe * 4];
        float sc = lpe * cm;
        w_s[wave][lane] = make_float4(w4.x * sc, w4.y * sc, w4.z * sc, w4.w * sc);
        moff_s[wave][lane] = mem * DIM;
    }
    __syncthreads();

    int half = lane >> 5;                // 0: even neighbors, 1: odd
    int l5 = lane & 31;                  // owns channels l5*8 .. l5*8+7
    const u16* fb = featb + (size_t)b * NTOK * DIM + l5 * 8;

    floatx2 acc2[8][2] = {};
    // 24 neighbor-pairs in 4 chunks of 6: explicit load staging for MLP
#pragma unroll
    for (int ch = 0; ch < 4; ++ch) {
        uint4 d[6];
        float4 wv6[6];
#pragma unroll
        for (int i = 0; i < 6; ++i) {
            int k = ch * 12 + 2 * i + half;
            d[i] = *(const uint4*)(fb + moff_s[wave][k]);
            wv6[i] = w_s[wave][k];
        }
#pragma unroll
        for (int i = 0; i < 6; ++i) {
            uint4 u = d[i];
            float4 w = wv6[i];
            floatx2 wA = {w.x, w.y};
            floatx2 wB = {w.z, w.w};
            float c[8];
            c[0] = asf(u.x << 16); c[1] = asf(u.x & 0xFFFF0000u);
            c[2] = asf(u.y << 16); c[3] = asf(u.y & 0xFFFF0000u);
            c[4] = asf(u.z << 16); c[5] = asf(u.z & 0xFFFF0000u);
            c[6] = asf(u.w << 16); c[7] = asf(u.w & 0xFFFF0000u);
#pragma unroll
            for (int j = 0; j < 8; ++j) {
                floatx2 cs = {c[j], c[j]};
                acc2[j][0] = __builtin_elementwise_fma(wA, cs, acc2[j][0]);
                acc2[j][1] = __builtin_elementwise_fma(wB, cs, acc2[j][1]);
            }
        }
    }

    // combine even/odd halves: lane l <-> lane l^32
#pragma unroll
    for (int j = 0; j < 8; ++j)
#pragma unroll
        for (int p = 0; p < 2; ++p) {
            acc2[j][p][0] += __shfl_xor(acc2[j][p][0], 32, 64);
            acc2[j][p][1] += __shfl_xor(acc2[j][p][1], 32, 64);
        }

    // in-wave LN (each value is duplicated across halves -> /2048)
    float s1 = 0.0f, s2 = 0.0f;
#pragma unroll
    for (int j = 0; j < 8; ++j)
#pragma unroll
        for (int p = 0; p < 2; ++p) {
            float v0 = acc2[j][p][0], v1 = acc2[j][p][1];
            s1 += v0 + v1;
            s2 += v0 * v0 + v1 * v1;
        }
#pragma unroll
    for (int off = 32; off > 0; off >>= 1) {
        s1 += __shfl_xor(s1, off, 64);
        s2 += __shfl_xor(s2, off, 64);
    }
    float mean = s1 * (1.0f / 2048.0f);
    float var = fmaxf(s2 * (1.0f / 2048.0f) - mean * mean, 0.0f);
    float rstd = rsqrtf(var + 1e-5f);

    // store: lanes<32 write m rows 0,1; lanes>=32 write m rows 2,3
    u16* Xp = xdst + (size_t)t * 1024;
    int cc0 = (half * 2) * 256 + l5 * 8;
    {
        float4 g0 = *(const float4*)&norm_g[cc0];
        float4 g1 = *(const float4*)&norm_g[cc0 + 4];
        float4 b0 = *(const float4*)&norm_b[cc0];
        float4 b1 = *(const float4*)&norm_b[cc0 + 4];
        float ga[8] = {g0.x, g0.y, g0.z, g0.w, g1.x, g1.y, g1.z, g1.w};
        float ba[8] = {b0.x, b0.y, b0.z, b0.w, b1.x, b1.y, b1.z, b1.w};
        union { uint4 v; u16 h[8]; } pk;
#pragma unroll
        for (int j = 0; j < 8; ++j) {
            floatx2 v2 = half ? acc2[j][1] : acc2[j][0];
            pk.h[j] = f2bf((v2[0] - mean) * rstd * ga[j] + ba[j]);
        }
        *(uint4*)(Xp + cc0) = pk.v;
    }
    {
        int cc1 = cc0 + 256;
        float4 g0 = *(const float4*)&norm_g[cc1];
        float4 g1 = *(const float4*)&norm_g[cc1 + 4];
        float4 b0 = *(const float4*)&norm_b[cc1];
        float4 b1 = *(const float4*)&norm_b[cc1 + 4];
        float ga[8] = {g0.x, g0.y, g0.z, g0.w, g1.x, g1.y, g1.z, g1.w};
        float ba[8] = {b0.x, b0.y, b0.z, b0.w, b1.x, b1.y, b1.z, b1.w};
        union { uint4 v; u16 h[8]; } pk;
#pragma unroll
        for (int j = 0; j < 8; ++j) {
            floatx2 v2 = half ? acc2[j][1] : acc2[j][0];
            pk.h[j] = f2bf((v2[1] - mean) * rstd * ga[j] + ba[j]);
        }
        *(uint4*)(Xp + cc1) = pk.v;
    }
}

// ---- K5 v5: 128x128 LDS-tiled GEMM, chunked XCD remap, 2-phase prefetch ---
#define GROW 40   // padded LDS row stride (halves)
__global__ __launch_bounds__(256) void gemm_tile_kernel(
    const u16* __restrict__ xws, const u16* __restrict__ linT,
    const float* __restrict__ lin_b, float* __restrict__ out) {
    __shared__ __align__(16) u16 As[128 * GROW];    // 10.2 KB
    __shared__ __align__(16) u16 Bs[128 * GROW];    // 10.2 KB
    // chunked XCD-affine remap: each XCD owns 49 contiguous tiles, n-fastest,
    // so its A-row band (~3.2 MB) streams through its own L2 exactly once.
    int bid = blockIdx.x;                // 392 = 98m x 4n tiles
    int xcd = bid & 7, kk8 = bid >> 3;   // kk8 in [0,49)
    int tile = xcd * 49 + kk8;
    int m0 = (tile >> 2) * 128, n0 = (tile & 3) * 128;

    int tid = threadIdx.x;
    int wave = tid >> 6, lane = tid & 63;
    int l15 = lane & 15, quad = lane >> 4;
    int wm = wave >> 1, wn = wave & 1;
    int sr = tid >> 2, sk = (tid & 3) * 8;          // 64 rows x 4 chunks per pass

    const u16* Ap0 = xws + (size_t)(m0 + sr) * 1024 + sk;
    const u16* Ap1 = Ap0 + (size_t)64 * 1024;
    const u16* Bp0 = linT + (size_t)(n0 + sr) * 1024 + sk;
    const u16* Bp1 = Bp0 + (size_t)64 * 1024;

    // prologue: stage tile 0 in registers
    uint4 a0 = *(const uint4*)(Ap0);
    uint4 a1 = *(const uint4*)(Ap1);
    uint4 b0 = *(const uint4*)(Bp0);
    uint4 b1 = *(const uint4*)(Bp1);

    floatx4 acc[4][4] = {};
    for (int kk = 0; kk < 1024; kk += 32) {
        __syncthreads();                  // prev tile's LDS reads done
        *(uint4*)&As[sr * GROW + sk] = a0;
        *(uint4*)&As[(64 + sr) * GROW + sk] = a1;
        *(uint4*)&Bs[sr * GROW + sk] = b0;
        *(uint4*)&Bs[(64 + sr) * GROW + sk] = b1;
        __syncthreads();
        if (kk + 32 < 1024) {             // issue next-tile loads before MFMA:
            a0 = *(const uint4*)(Ap0 + kk + 32);   // HBM latency hides under
            a1 = *(const uint4*)(Ap1 + kk + 32);   // the ds_read+MFMA cluster
            b0 = *(const uint4*)(Bp0 + kk + 32);
            b1 = *(const uint4*)(Bp1 + kk + 32);
        }
        bf16x8 af[4], bfv[4];
#pragma unroll
        for (int mi = 0; mi < 4; ++mi)
            af[mi] = *(const bf16x8*)&As[(wm * 64 + mi * 16 + l15) * GROW + quad * 8];
#pragma unroll
        for (int ni = 0; ni < 4; ++ni)
            bfv[ni] = *(const bf16x8*)&Bs[(wn * 64 + ni * 16 + l15) * GROW + quad * 8];
#pragma unroll
        for (int mi = 0; mi < 4; ++mi)
#pragma unroll
            for (int ni = 0; ni < 4; ++ni)
                acc[mi][ni] = __builtin_amdgcn_mfma_f32_16x16x32_bf16(
                    af[mi], bfv[ni], acc[mi][ni], 0, 0, 0);
    }
#pragma unroll
    for (int ni = 0; ni < 4; ++ni) {
        int col = n0 + wn * 64 + ni * 16 + l15;
        float bias = lin_b[col];
#pragma unroll
        for (int mi = 0; mi < 4; ++mi)
#pragma unroll
            for (int reg = 0; reg < 4; ++reg) {
                int row = m0 + wm * 64 + mi * 16 + quad * 4 + reg;
                out[(size_t)row * OUTD + col] = acc[mi][ni][reg] + bias;
            }
    }
}

// ---- fallback kernels (zero-workspace, round-3 proven) --------------------
__global__ __launch_bounds__(256) void key_kernel(
    const float* __restrict__ lprob, u64* __restrict__ keys) {
    int g = blockIdx.x * 256 + threadIdx.x;
    int n = g % NTOK;
    keys[g] = f_to_key(make_f(lprob[g], n), n);
}

__global__ __launch_bounds__(256) void partial_rank_kernel(
    const u64* __restrict__ keys, u32* __restrict__ part) {
    int b = blockIdx.y, z = blockIdx.z;
    int n = blockIdx.x * 256 + threadIdx.x;
    u64 my = keys[b * NTOK + n];
    const u64* kb = keys + b * NTOK + z * QTR;
    u32 cnt = 0;
    for (int t = 0; t < QTR; t += 8) {
#pragma unroll
        for (int j = 0; j < 8; ++j) cnt += (kb[t + j] > my) ? 1u : 0u;
    }
    part[(z * NB + b) * NTOK + n] = cnt;
}

__global__ __launch_bounds__(256) void finalize_kernel(
    const u32* __restrict__ part, float* __restrict__ pos_out) {
    int b = blockIdx.y;
    int n = blockIdx.x * 256 + threadIdx.x;
    int g = b * NTOK + n;
    u32 rank = part[g] + part[(NB + b) * NTOK + n] +
               part[(2 * NB + b) * NTOK + n] + part[(3 * NB + b) * NTOK + n];
    int i = n / GW, j = n % GW;
    if (rank < SAMPLEN) {
        int slot = b * KEEPN + (int)rank;
        pos_out[slot * 2 + 0] = (float)i;
        pos_out[slot * 2 + 1] = (float)j;
    }
    if (((i | j) & 3) == 0) {
        int r = (i >> 2) * 28 + (j >> 2);
        int slot = b * KEEPN + SAMPLEN + r;
        pos_out[slot * 2 + 0] = (float)i;
        pos_out[slot * 2 + 1] = (float)j;
    }
}

__global__ __launch_bounds__(256) void token_fb_kernel(
    const float* __restrict__ pos_in, u16* __restrict__ xdst,
    const int* __restrict__ member_idx, const int* __restrict__ pe_idx,
    const float* __restrict__ cmask, const float* __restrict__ lprob,
    const float* __restrict__ featf, const float* __restrict__ pre_table,
    const float* __restrict__ w1, const float* __restrict__ b1,
    const float* __restrict__ g1, const float* __restrict__ bb1,
    const float* __restrict__ norm_g, const float* __restrict__ norm_b) {
    int t = blockIdx.x;
    int b = t / KEEPN;
    int tid = threadIdx.x;
    __shared__ int mem_s[NBHD];
    __shared__ float4 w_s[NBHD];
    __shared__ float red[10];

    int n_src = (int)pos_in[t * 2 + 0] * GW + (int)pos_in[t * 2 + 1];

    if (tid < NBHD) {
        int e = (b * NTOK + n_src) * NBHD + tid;
        int mem = member_idx[e];
        int pe = pe_idx[e];
        float cm = cmask[e];
        float lpe = lprob[b * NTOK + mem];
        float z[4];
#pragma unroll
        for (int m = 0; m < 4; ++m) {
            float acc = b1[m];
#pragma unroll
            for (int d = 0; d < 5; ++d) acc += pre_table[pe * 5 + d] * w1[d * 4 + m];
            z[m] = acc;
        }
        float mean = (z[0] + z[1] + z[2] + z[3]) * 0.25f;
        float var = 0.0f;
#pragma unroll
        for (int m = 0; m < 4; ++m) { float d = z[m] - mean; var += d * d; }
        float rstd = rsqrtf(var * 0.25f + 1e-5f);
        float sc = lpe * cm;
        float wv[4];
#pragma unroll
        for (int m = 0; m < 4; ++m) {
            float y = (z[m] - mean) * rstd * g1[m] + bb1[m];
            wv[m] = 0.5f * y * (1.0f + erff(y * 0.70710678118654752f)) * sc;
        }
        w_s[tid] = make_float4(wv[0], wv[1], wv[2], wv[3]);
        mem_s[tid] = mem;
    }
    __syncthreads();

    float a0 = 0.f, a1 = 0.f, a2 = 0.f, a3 = 0.f;
    size_t base = (size_t)b * NTOK * DIM + tid;
#pragma unroll 8
    for (int k = 0; k < NBHD; ++k) {
        float g = featf[base + (size_t)mem_s[k] * DIM];
        float4 w = w_s[k];
        a0 += w.x * g; a1 += w.y * g; a2 += w.z * g; a3 += w.w * g;
    }
    float s1 = a0 + a1 + a2 + a3;
    float s2 = a0 * a0 + a1 * a1 + a2 * a2 + a3 * a3;
#pragma unroll
    for (int off = 32; off > 0; off >>= 1) {
        s1 += __shfl_down(s1, off, 64);
        s2 += __shfl_down(s2, off, 64);
    }
    int wave = tid >> 6, lane = tid & 63;
    if (lane == 0) { red[wave] = s1; red[4 + wave] = s2; }
    __syncthreads();
    if (tid == 0) {
        float S = red[0] + red[1] + red[2] + red[3];
        float Q = red[4] + red[5] + red[6] + red[7];
        float mean = S * (1.0f / 1024.0f);
        float var = fmaxf(Q * (1.0f / 1024.0f) - mean * mean, 0.0f);
        red[8] = mean; red[9] = rsqrtf(var + 1e-5f);
    }
    __syncthreads();
    float mean = red[8], rstd = red[9];
    float acc4[4] = {a0, a1, a2, a3};
    u16* Xp = xdst + (size_t)t * 1024;
#pragma unroll
    for (int m = 0; m < 4; ++m) {
        int cc = m * 256 + tid;
        float v = (acc4[m] - mean) * rstd * norm_g[cc] + norm_b[cc];
        Xp[cc] = f2bf(v);
    }
}

__global__ __launch_bounds__(256) void gemm_inplace_kernel(
    const float* __restrict__ lin_w, const float* __restrict__ lin_b,
    float* __restrict__ out) {
    __shared__ __align__(16) u16 Bs[BLKN * BROW];
    int tile_m = blockIdx.x;
    int nblk = blockIdx.y;
    int tid = threadIdx.x;
    int wave = tid >> 6, lane = tid & 63;
    int l15 = lane & 15, quad = lane >> 4;

    const u16* Xbase = (const u16*)out;
    floatx4 acc[8][4] = {};

    for (int kk = 0; kk < 1024; kk += 32) {
        __syncthreads();
#pragma unroll
        for (int it = 0; it < 4; ++it) {
            int task = it * 256 + tid;
            int kp = task >> 6;
            int ng = task & 63;
            int k = kp * 2;
            int n0 = nblk * BLKN + ng * 4;
            float4 fa = *(const float4*)&lin_w[(size_t)(kk + k) * OUTD + n0];
            float4 fb = *(const float4*)&lin_w[(size_t)(kk + k + 1) * OUTD + n0];
            u16* bp = &Bs[(ng * 4) * BROW + k];
            *(u32*)(bp + 0 * BROW) = (u32)f2bf(fa.x) | ((u32)f2bf(fb.x) << 16);
            *(u32*)(bp + 1 * BROW) = (u32)f2bf(fa.y) | ((u32)f2bf(fb.y) << 16);
            *(u32*)(bp + 2 * BROW) = (u32)f2bf(fa.z) | ((u32)f2bf(fb.z) << 16);
            *(u32*)(bp + 3 * BROW) = (u32)f2bf(fa.w) | ((u32)f2bf(fb.w) << 16);
        }
        __syncthreads();
        bf16x8 bfrag[4];
#pragma unroll
        for (int ni = 0; ni < 4; ++ni)
            bfrag[ni] = *(const bf16x8*)&Bs[(wave * 64 + ni * 16 + l15) * BROW + quad * 8];
#pragma unroll
        for (int mi = 0; mi < 8; ++mi) {
            int row = tile_m * BLKM + mi * 16 + l15;
            bf16x8 af = *(const bf16x8*)&Xbase[(size_t)row * 1024 + kk + quad * 8];
#pragma unroll
            for (int ni = 0; ni < 4; ++ni)
                acc[mi][ni] = __builtin_amdgcn_mfma_f32_16x16x32_bf16(
                    af, bfrag[ni], acc[mi][ni], 0, 0, 0);
        }
    }
    __syncthreads();
#pragma unroll
    for (int mi = 0; mi < 8; ++mi)
#pragma unroll
        for (int ni = 0; ni < 4; ++ni) {
            int col = nblk * BLKN + wave * 64 + ni * 16 + l15;
            float bias = lin_b[col];
#pragma unroll
            for (int reg = 0; reg < 4; ++reg) {
                int row = tile_m * BLKM + mi * 16 + quad * 4 + reg;
                out[(size_t)row * OUTD + col] = acc[mi][ni][reg] + bias;
            }
        }
}

extern "C" void kernel_launch(void* const* d_in, const int* in_sizes, int n_in,
                              void* d_out, int out_size, void* d_ws, size_t ws_size,
                              hipStream_t stream) {
    const float* feat     = (const float*)d_in[1];
    const int* member_idx = (const int*)d_in[2];
    const float* cmask    = (const float*)d_in[3];
    const float* lprob    = (const float*)d_in[4];
    const int* pe_idx     = (const int*)d_in[6];
    const float* pre_table= (const float*)d_in[8];
    const float* w1       = (const float*)d_in[9];
    const float* b1       = (const float*)d_in[10];
    const float* g1       = (const float*)d_in[11];
    const float* bb1      = (const float*)d_in[12];
    const float* norm_g   = (const float*)d_in[13];
    const float* norm_b   = (const float*)d_in[14];
    const float* lin_w    = (const float*)d_in[15];
    const float* lin_b    = (const float*)d_in[16];

    float* pos_out = (float*)d_out;
    float* out     = pos_out + POSN;

    if (ws_size >= WS_NEED) {
        char* ws = (char*)d_ws;
        u16* featb = (u16*)ws;
        u16* xws   = (u16*)(ws + FEATB_BYTES);
        u16* linT  = (u16*)(ws + FEATB_BYTES + XWS_BYTES);
        u64* slots = (u64*)(ws + FEATB_BYTES + XWS_BYTES + LINT_BYTES);
        u32* hist  = (u32*)(ws + FEATB_BYTES + XWS_BYTES + LINT_BYTES + KEYS_BYTES);
        u32* base  = hist + NB * NBKT;
        u32* curs  = base + NB * NBKT;
        // wt table (TABLE x 4 f32 = 64 KB) lives at the head of the `out`
        // region: written by linT_cvt, read by token_v4, overwritten by gemm.
        float* wtbuf = out;

        feat_cvt_kernel<<<12544, 256, 0, stream>>>(feat, featb);
        linT_cvt_kernel<<<dim3(16, 8), 256, 0, stream>>>(
            lin_w, linT, hist, pre_table, w1, b1, g1, bb1, wtbuf);
        hist_kernel<<<(NB * NTOK) / 256, 256, 0, stream>>>(lprob, hist);
        prefix_kernel<<<NB, 1024, 0, stream>>>(hist, base, curs);
        scatter_kernel<<<(NB * NTOK) / 256, 256, 0, stream>>>(lprob, curs, slots);
        rank_finalize_kernel<<<(NB * NTOK) / 256, 256, 0, stream>>>(
            lprob, hist, base, slots, pos_out);
        token_v4_kernel<<<(NB * KEEPN) / 4, 256, 0, stream>>>(
            pos_out, xws, member_idx, pe_idx, cmask, lprob, featb,
            wtbuf, norm_g, norm_b);
        gemm_tile_kernel<<<392, 256, 0, stream>>>(xws, linT, lin_b, out);
    } else {
        u64* keys = (u64*)out;
        u32* part = (u32*)((char*)out + 401408);

        key_kernel<<<(NB * NTOK) / 256, 256, 0, stream>>>(lprob, keys);
        partial_rank_kernel<<<dim3(49, NB, 4), 256, 0, stream>>>(keys, part);
        finalize_kernel<<<dim3(49, NB), 256, 0, stream>>>(part, pos_out);
        token_fb_kernel<<<NB * KEEPN, 256, 0, stream>>>(
            pos_out, (u16*)out, member_idx, pe_idx, cmask, lprob, feat,
            pre_table, w1, b1, g1, bb1, norm_g, norm_b);
        gemm_inplace_kernel<<<dim3(98, 2), 256, 0, stream>>>(lin_w, lin_b, out);
    }
}

// Round 3
// 240.969 us; speedup vs baseline: 1.3485x; 1.3485x over previous
//
#include <hip/hip_runtime.h>

typedef unsigned short u16;
typedef unsigned int u32;
typedef unsigned long long u64;

#define NB 4
#define NTOK 12544
#define NBHD 48
#define DIM 256
#define OUTD 512
#define KEEPN 3136
#define SAMPLEN 2352
#define RESN 784
#define GW 112
#define TABLE 4096
#define POSN (NB * KEEPN * 2)   // 25088 floats
#define QTR (NTOK / 4)          // 3136
#define NBKT 16384

// fallback in-place GEMM tiling
#define BLKM 128
#define BLKN 256
#define BROW 40

// ws fast-path layout (bytes)
#define FEATB_BYTES (25690112ull)                 // 4*12544*256*2
#define XWS_BYTES   (25690112ull)                 // 12544*1024*2
#define LINT_BYTES  (1048576ull)                  // 512*1024*2
#define KEYS_BYTES  (401408ull)                   // slots: 4*12544*8
#define PART_BYTES  (802816ull)                   // hist+base+cursor: 786432 used
#define WS_NEED (FEATB_BYTES + XWS_BYTES + LINT_BYTES + KEYS_BYTES + PART_BYTES)

__device__ __forceinline__ float bf2f(u16 u) {
    union { u32 i; float f; } v; v.i = ((u32)u) << 16; return v.f;
}
__device__ __forceinline__ float asf(u32 u) {
    union { u32 i; float f; } v; v.i = u; return v.f;
}
__device__ __forceinline__ u16 f2bf(float f) {
    union { u32 i; float f; } v; v.f = f;
    return (u16)((v.i + 0x7FFFu + ((v.i >> 16) & 1u)) >> 16);
}

typedef __bf16 bf16x8 __attribute__((ext_vector_type(8)));
typedef float floatx4 __attribute__((ext_vector_type(4)));
typedef float floatx2 __attribute__((ext_vector_type(2)));

// final_prob, bit-exact vs reference f32 arithmetic
__device__ __forceinline__ float make_f(float lp, int n) {
    int i = n / GW, j = n % GW;
    float f = lp * 4.0f;
    if (((i | j) & 1) == 0) f = 1.0f + f;        // grid_prob (stride 2)
    if (((i | j) & 3) == 0) f = f + (-100.0f);   // reserve penalty (stride 4)
    return f;
}
// key: descending order == top_k order; ties -> lower n first
__device__ __forceinline__ u64 f_to_key(float f, int n) {
    union { float f; u32 u; } v; v.f = f;
    u32 m = (v.u & 0x80000000u) ? ~v.u : (v.u | 0x80000000u);
    return (((u64)m) << 32) | (u64)(0xFFFFFFFFu - (u32)n);
}
__device__ __forceinline__ int f_to_bucket(float f) {
    int b = (int)floorf(f * 3276.8f);            // monotone: [0,5) -> [0,16384)
    return b < 0 ? 0 : (b > NBKT - 1 ? NBKT - 1 : b);
}

// ---- convert feat f32 -> bf16 ---------------------------------------------
__global__ __launch_bounds__(256) void feat_cvt_kernel(
    const float* __restrict__ feat, u16* __restrict__ featb) {
    int t = blockIdx.x * 256 + threadIdx.x;
    float4 v = ((const float4*)feat)[t];
    u64 w = (u64)f2bf(v.x) | ((u64)f2bf(v.y) << 16) |
            ((u64)f2bf(v.z) << 32) | ((u64)f2bf(v.w) << 48);
    ((u64*)featb)[t] = w;
}

// ---- convert+transpose lin_w -> linT (512x1024 bf16); zero hist;
// ---- fused weight_net table precompute: wt[TABLE][4] = gelu(ln(pt@w1+b1))
__global__ __launch_bounds__(256) void linT_cvt_kernel(
    const float* __restrict__ lin_w, u16* __restrict__ linT,
    u32* __restrict__ hist,
    const float* __restrict__ pre_table, const float* __restrict__ w1,
    const float* __restrict__ b1, const float* __restrict__ g1,
    const float* __restrict__ bb1, float* __restrict__ wt) {
    __shared__ u16 T[64 * 65];
    int k0 = blockIdx.x * 64, n0 = blockIdx.y * 64;
    int t = threadIdx.x;
    int bid = blockIdx.y * 16 + blockIdx.x;
    // fused hist zeroing: 128 blocks x 512 entries = 65536
    hist[bid * 512 + t] = 0;
    hist[bid * 512 + 256 + t] = 0;
    // fused wt precompute: first 16 blocks cover TABLE=4096 rows
    int gid = bid * 256 + t;
    if (gid < TABLE) {
        float z[4];
#pragma unroll
        for (int m = 0; m < 4; ++m) {
            float acc = b1[m];
#pragma unroll
            for (int d = 0; d < 5; ++d) acc += pre_table[gid * 5 + d] * w1[d * 4 + m];
            z[m] = acc;
        }
        float mean = (z[0] + z[1] + z[2] + z[3]) * 0.25f;
        float var = 0.0f;
#pragma unroll
        for (int m = 0; m < 4; ++m) { float d = z[m] - mean; var += d * d; }
        float rstd = rsqrtf(var * 0.25f + 1e-5f);
        float wv[4];
#pragma unroll
        for (int m = 0; m < 4; ++m) {
            float y = (z[m] - mean) * rstd * g1[m] + bb1[m];
            wv[m] = 0.5f * y * (1.0f + erff(y * 0.70710678118654752f));
        }
        *(float4*)&wt[gid * 4] = make_float4(wv[0], wv[1], wv[2], wv[3]);
    }
    int r = t >> 2, c4 = (t & 3) * 16;
#pragma unroll
    for (int i = 0; i < 4; ++i) {
        float4 v = *(const float4*)&lin_w[(size_t)(k0 + r) * OUTD + n0 + c4 + i * 4];
        T[(c4 + i * 4 + 0) * 65 + r] = f2bf(v.x);
        T[(c4 + i * 4 + 1) * 65 + r] = f2bf(v.y);
        T[(c4 + i * 4 + 2) * 65 + r] = f2bf(v.z);
        T[(c4 + i * 4 + 3) * 65 + r] = f2bf(v.w);
    }
    __syncthreads();
    int nl = t >> 2, kc = (t & 3) * 16;
    union { uint4 v[2]; u16 h[16]; } u;
#pragma unroll
    for (int i = 0; i < 16; ++i) u.h[i] = T[nl * 65 + kc + i];
    u16* dst = &linT[(size_t)(n0 + nl) * 1024 + k0 + kc];
    *(uint4*)(dst + 0) = u.v[0];
    *(uint4*)(dst + 8) = u.v[1];
}

// ================= selection: exact counting-sort top-k =====================
__global__ __launch_bounds__(256) void hist_kernel(
    const float* __restrict__ lprob, u32* __restrict__ hist) {
    int g = blockIdx.x * 256 + threadIdx.x;        // 196 blocks
    int b = g / NTOK, n = g % NTOK;
    int bkt = f_to_bucket(make_f(lprob[g], n));
    atomicAdd(&hist[b * NBKT + bkt], 1u);
}

// descending exclusive prefix: base[e] = #keys in buckets > e
__global__ __launch_bounds__(1024) void prefix_kernel(
    const u32* __restrict__ hist, u32* __restrict__ base, u32* __restrict__ cursor) {
    int b = blockIdx.x, t = threadIdx.x;
    const u32* h = hist + b * NBKT;
    u32 loc[16], own = 0;
#pragma unroll
    for (int i = 0; i < 16; ++i) { loc[i] = h[t * 16 + i]; own += loc[i]; }
    __shared__ u32 buf[2][1024];
    buf[0][t] = own;
    __syncthreads();
    int src = 0;
    for (int off = 1; off < 1024; off <<= 1) {
        u32 v = buf[src][t] + ((t + off < 1024) ? buf[src][t + off] : 0u);
        buf[src ^ 1][t] = v;
        src ^= 1;
        __syncthreads();
    }
    u32 above = buf[src][t] - own;                 // chunks strictly after t
    u32 suf = 0, bout[16];
    for (int i = 15; i >= 0; --i) { bout[i] = above + suf; suf += loc[i]; }
    u32* bb = base + b * NBKT;
    u32* cc = cursor + b * NBKT;
#pragma unroll
    for (int i = 0; i < 16; ++i) { bb[t * 16 + i] = bout[i]; cc[t * 16 + i] = bout[i]; }
}

__global__ __launch_bounds__(256) void scatter_kernel(
    const float* __restrict__ lprob, u32* __restrict__ cursor,
    u64* __restrict__ slots) {
    int g = blockIdx.x * 256 + threadIdx.x;
    int b = g / NTOK, n = g % NTOK;
    float f = make_f(lprob[g], n);
    int bkt = f_to_bucket(f);
    u32 s = atomicAdd(&cursor[b * NBKT + bkt], 1u);
    slots[b * NTOK + s] = f_to_key(f, n);
}

__global__ __launch_bounds__(256) void rank_finalize_kernel(
    const float* __restrict__ lprob, const u32* __restrict__ hist,
    const u32* __restrict__ base, const u64* __restrict__ slots,
    float* __restrict__ pos_out) {
    int g = blockIdx.x * 256 + threadIdx.x;
    int b = g / NTOK, n = g % NTOK;
    int i = n / GW, j = n % GW;
    if (((i | j) & 3) == 0) {
        // reserve token: rank >= 11760 > SAMPLEN always; fills fixed tail slot
        int r = (i >> 2) * 28 + (j >> 2);
        int slot = b * KEEPN + SAMPLEN + r;
        pos_out[slot * 2 + 0] = (float)i;
        pos_out[slot * 2 + 1] = (float)j;
        return;
    }
    float f = make_f(lprob[g], n);
    int bkt = f_to_bucket(f);
    u32 r0 = base[b * NBKT + bkt];
    if (r0 >= SAMPLEN) return;                     // whole bucket below cut
    u64 my = f_to_key(f, n);
    u32 cnt = hist[b * NBKT + bkt];
    const u64* sl = slots + b * NTOK + r0;
    u32 rank = r0;
    for (u32 s = 0; s < cnt; ++s) rank += (sl[s] > my) ? 1u : 0u;
    if (rank < SAMPLEN) {
        int slot = b * KEEPN + (int)rank;
        pos_out[slot * 2 + 0] = (float)i;
        pos_out[slot * 2 + 1] = (float)j;
    }
}

// ---- K4 v5: wave-per-token gather (v3 skeleton) + packed-f32 FMA ----------
// accA[c] = (m0,m1) for channel c, accB[c] = (m2,m3): 8 v_pk_fma_f32/neighbor
__global__ __launch_bounds__(256) void token_v5_kernel(
    const float* __restrict__ pos_in, u16* __restrict__ xdst,
    const int* __restrict__ member_idx, const int* __restrict__ pe_idx,
    const float* __restrict__ cmask, const float* __restrict__ lprob,
    const u16* __restrict__ featb, const float* __restrict__ wt,
    const float* __restrict__ norm_g, const float* __restrict__ norm_b) {
    // XCD-affinity: block i -> xcd i&7 (round-robin dispatch);
    // batch b owns xcds {2b, 2b+1} so per-XCD hot set = 6.4 MB.
    int bi = blockIdx.x;                 // 3136 blocks, 4 tokens each
    int xcd = bi & 7, jj = bi >> 3;      // jj in [0,392)
    int b = xcd >> 1;
    int tid = threadIdx.x;
    int wave = tid >> 6, lane = tid & 63;
    int t = b * KEEPN + (xcd & 1) * 1568 + jj * 4 + wave;

    __shared__ float4 w_s[4][NBHD];
    __shared__ int moff_s[4][NBHD];      // mem*DIM (u16-element offset)

    float2 pp = *(const float2*)&pos_in[t * 2];
    int n_src = (int)pp.x * GW + (int)pp.y;

    if (lane < NBHD) {
        int e = (b * NTOK + n_src) * NBHD + lane;
        int mem = member_idx[e];
        int pe = pe_idx[e];
        float cm = cmask[e];
        float lpe = lprob[b * NTOK + mem];
        float4 w4 = *(const float4*)&wt[pe * 4];
        float sc = lpe * cm;
        w_s[wave][lane] = make_float4(w4.x * sc, w4.y * sc, w4.z * sc, w4.w * sc);
        moff_s[wave][lane] = mem * DIM;
    }
    __syncthreads();

    // lane owns channels lane*4 .. lane*4+3
    floatx2 accA[4] = {};   // channel j -> (m0, m1)
    floatx2 accB[4] = {};   // channel j -> (m2, m3)
    const u16* fbase = featb + (size_t)b * NTOK * DIM + lane * 4;
#pragma unroll 8
    for (int k = 0; k < NBHD; ++k) {
        uint2 d = *(const uint2*)(fbase + (size_t)moff_s[wave][k]);
        float4 w = w_s[wave][k];
        floatx2 w01 = {w.x, w.y};
        floatx2 w23 = {w.z, w.w};
        float c0 = asf(d.x << 16);
        float c1 = asf(d.x & 0xFFFF0000u);
        float c2 = asf(d.y << 16);
        float c3 = asf(d.y & 0xFFFF0000u);
        floatx2 c0v = {c0, c0}, c1v = {c1, c1}, c2v = {c2, c2}, c3v = {c3, c3};
        accA[0] = __builtin_elementwise_fma(w01, c0v, accA[0]);
        accB[0] = __builtin_elementwise_fma(w23, c0v, accB[0]);
        accA[1] = __builtin_elementwise_fma(w01, c1v, accA[1]);
        accB[1] = __builtin_elementwise_fma(w23, c1v, accB[1]);
        accA[2] = __builtin_elementwise_fma(w01, c2v, accA[2]);
        accB[2] = __builtin_elementwise_fma(w23, c2v, accB[2]);
        accA[3] = __builtin_elementwise_fma(w01, c3v, accA[3]);
        accB[3] = __builtin_elementwise_fma(w23, c3v, accB[3]);
    }

    // in-wave LN over the token's 1024 values
    float s1 = 0.0f, s2 = 0.0f;
#pragma unroll
    for (int j = 0; j < 4; ++j) {
        float v0 = accA[j][0], v1 = accA[j][1], v2 = accB[j][0], v3 = accB[j][1];
        s1 += v0 + v1 + v2 + v3;
        s2 += v0 * v0 + v1 * v1 + v2 * v2 + v3 * v3;
    }
#pragma unroll
    for (int off = 32; off > 0; off >>= 1) {
        s1 += __shfl_xor(s1, off, 64);
        s2 += __shfl_xor(s2, off, 64);
    }
    float mean = s1 * (1.0f / 1024.0f);
    float var = fmaxf(s2 * (1.0f / 1024.0f) - mean * mean, 0.0f);
    float rstd = rsqrtf(var + 1e-5f);

    u16* Xp = xdst + (size_t)t * 1024;
#pragma unroll
    for (int m = 0; m < 4; ++m) {
        int cc = m * 256 + lane * 4;
        float4 g4 = *(const float4*)&norm_g[cc];
        float4 b4 = *(const float4*)&norm_b[cc];
        float v0 = (m == 0) ? accA[0][0] : (m == 1) ? accA[0][1]
                 : (m == 2) ? accB[0][0] : accB[0][1];
        float v1 = (m == 0) ? accA[1][0] : (m == 1) ? accA[1][1]
                 : (m == 2) ? accB[1][0] : accB[1][1];
        float v2 = (m == 0) ? accA[2][0] : (m == 1) ? accA[2][1]
                 : (m == 2) ? accB[2][0] : accB[2][1];
        float v3 = (m == 0) ? accA[3][0] : (m == 1) ? accA[3][1]
                 : (m == 2) ? accB[3][0] : accB[3][1];
        u16 h0 = f2bf((v0 - mean) * rstd * g4.x + b4.x);
        u16 h1 = f2bf((v1 - mean) * rstd * g4.y + b4.y);
        u16 h2 = f2bf((v2 - mean) * rstd * g4.z + b4.z);
        u16 h3 = f2bf((v3 - mean) * rstd * g4.w + b4.w);
        u64 w = (u64)h0 | ((u64)h1 << 16) | ((u64)h2 << 32) | ((u64)h3 << 48);
        *(u64*)(Xp + cc) = w;
    }
}

// ---- K5 v5: 128x128 LDS-tiled GEMM, chunked XCD remap, 2-phase prefetch ---
#define GROW 40   // padded LDS row stride (halves)
__global__ __launch_bounds__(256) void gemm_tile_kernel(
    const u16* __restrict__ xws, const u16* __restrict__ linT,
    const float* __restrict__ lin_b, float* __restrict__ out) {
    __shared__ __align__(16) u16 As[128 * GROW];    // 10.2 KB
    __shared__ __align__(16) u16 Bs[128 * GROW];    // 10.2 KB
    // chunked XCD-affine remap: each XCD owns 49 contiguous tiles, n-fastest,
    // so its A-row band (~3.2 MB) streams through its own L2 exactly once.
    int bid = blockIdx.x;                // 392 = 98m x 4n tiles
    int xcd = bid & 7, kk8 = bid >> 3;   // kk8 in [0,49)
    int tile = xcd * 49 + kk8;
    int m0 = (tile >> 2) * 128, n0 = (tile & 3) * 128;

    int tid = threadIdx.x;
    int wave = tid >> 6, lane = tid & 63;
    int l15 = lane & 15, quad = lane >> 4;
    int wm = wave >> 1, wn = wave & 1;
    int sr = tid >> 2, sk = (tid & 3) * 8;          // 64 rows x 4 chunks per pass

    const u16* Ap0 = xws + (size_t)(m0 + sr) * 1024 + sk;
    const u16* Ap1 = Ap0 + (size_t)64 * 1024;
    const u16* Bp0 = linT + (size_t)(n0 + sr) * 1024 + sk;
    const u16* Bp1 = Bp0 + (size_t)64 * 1024;

    // prologue: stage tile 0 in registers
    uint4 a0 = *(const uint4*)(Ap0);
    uint4 a1 = *(const uint4*)(Ap1);
    uint4 b0 = *(const uint4*)(Bp0);
    uint4 b1 = *(const uint4*)(Bp1);

    floatx4 acc[4][4] = {};
    for (int kk = 0; kk < 1024; kk += 32) {
        __syncthreads();                  // prev tile's LDS reads done
        *(uint4*)&As[sr * GROW + sk] = a0;
        *(uint4*)&As[(64 + sr) * GROW + sk] = a1;
        *(uint4*)&Bs[sr * GROW + sk] = b0;
        *(uint4*)&Bs[(64 + sr) * GROW + sk] = b1;
        __syncthreads();
        if (kk + 32 < 1024) {             // issue next-tile loads before MFMA:
            a0 = *(const uint4*)(Ap0 + kk + 32);   // HBM latency hides under
            a1 = *(const uint4*)(Ap1 + kk + 32);   // the ds_read+MFMA cluster
            b0 = *(const uint4*)(Bp0 + kk + 32);
            b1 = *(const uint4*)(Bp1 + kk + 32);
        }
        bf16x8 af[4], bfv[4];
#pragma unroll
        for (int mi = 0; mi < 4; ++mi)
            af[mi] = *(const bf16x8*)&As[(wm * 64 + mi * 16 + l15) * GROW + quad * 8];
#pragma unroll
        for (int ni = 0; ni < 4; ++ni)
            bfv[ni] = *(const bf16x8*)&Bs[(wn * 64 + ni * 16 + l15) * GROW + quad * 8];
#pragma unroll
        for (int mi = 0; mi < 4; ++mi)
#pragma unroll
            for (int ni = 0; ni < 4; ++ni)
                acc[mi][ni] = __builtin_amdgcn_mfma_f32_16x16x32_bf16(
                    af[mi], bfv[ni], acc[mi][ni], 0, 0, 0);
    }
#pragma unroll
    for (int ni = 0; ni < 4; ++ni) {
        int col = n0 + wn * 64 + ni * 16 + l15;
        float bias = lin_b[col];
#pragma unroll
        for (int mi = 0; mi < 4; ++mi)
#pragma unroll
            for (int reg = 0; reg < 4; ++reg) {
                int row = m0 + wm * 64 + mi * 16 + quad * 4 + reg;
                out[(size_t)row * OUTD + col] = acc[mi][ni][reg] + bias;
            }
    }
}

// ---- fallback kernels (zero-workspace, round-3 proven) --------------------
__global__ __launch_bounds__(256) void key_kernel(
    const float* __restrict__ lprob, u64* __restrict__ keys) {
    int g = blockIdx.x * 256 + threadIdx.x;
    int n = g % NTOK;
    keys[g] = f_to_key(make_f(lprob[g], n), n);
}

__global__ __launch_bounds__(256) void partial_rank_kernel(
    const u64* __restrict__ keys, u32* __restrict__ part) {
    int b = blockIdx.y, z = blockIdx.z;
    int n = blockIdx.x * 256 + threadIdx.x;
    u64 my = keys[b * NTOK + n];
    const u64* kb = keys + b * NTOK + z * QTR;
    u32 cnt = 0;
    for (int t = 0; t < QTR; t += 8) {
#pragma unroll
        for (int j = 0; j < 8; ++j) cnt += (kb[t + j] > my) ? 1u : 0u;
    }
    part[(z * NB + b) * NTOK + n] = cnt;
}

__global__ __launch_bounds__(256) void finalize_kernel(
    const u32* __restrict__ part, float* __restrict__ pos_out) {
    int b = blockIdx.y;
    int n = blockIdx.x * 256 + threadIdx.x;
    int g = b * NTOK + n;
    u32 rank = part[g] + part[(NB + b) * NTOK + n] +
               part[(2 * NB + b) * NTOK + n] + part[(3 * NB + b) * NTOK + n];
    int i = n / GW, j = n % GW;
    if (rank < SAMPLEN) {
        int slot = b * KEEPN + (int)rank;
        pos_out[slot * 2 + 0] = (float)i;
        pos_out[slot * 2 + 1] = (float)j;
    }
    if (((i | j) & 3) == 0) {
        int r = (i >> 2) * 28 + (j >> 2);
        int slot = b * KEEPN + SAMPLEN + r;
        pos_out[slot * 2 + 0] = (float)i;
        pos_out[slot * 2 + 1] = (float)j;
    }
}

__global__ __launch_bounds__(256) void token_fb_kernel(
    const float* __restrict__ pos_in, u16* __restrict__ xdst,
    const int* __restrict__ member_idx, const int* __restrict__ pe_idx,
    const float* __restrict__ cmask, const float* __restrict__ lprob,
    const float* __restrict__ featf, const float* __restrict__ pre_table,
    const float* __restrict__ w1, const float* __restrict__ b1,
    const float* __restrict__ g1, const float* __restrict__ bb1,
    const float* __restrict__ norm_g, const float* __restrict__ norm_b) {
    int t = blockIdx.x;
    int b = t / KEEPN;
    int tid = threadIdx.x;
    __shared__ int mem_s[NBHD];
    __shared__ float4 w_s[NBHD];
    __shared__ float red[10];

    int n_src = (int)pos_in[t * 2 + 0] * GW + (int)pos_in[t * 2 + 1];

    if (tid < NBHD) {
        int e = (b * NTOK + n_src) * NBHD + tid;
        int mem = member_idx[e];
        int pe = pe_idx[e];
        float cm = cmask[e];
        float lpe = lprob[b * NTOK + mem];
        float z[4];
#pragma unroll
        for (int m = 0; m < 4; ++m) {
            float acc = b1[m];
#pragma unroll
            for (int d = 0; d < 5; ++d) acc += pre_table[pe * 5 + d] * w1[d * 4 + m];
            z[m] = acc;
        }
        float mean = (z[0] + z[1] + z[2] + z[3]) * 0.25f;
        float var = 0.0f;
#pragma unroll
        for (int m = 0; m < 4; ++m) { float d = z[m] - mean; var += d * d; }
        float rstd = rsqrtf(var * 0.25f + 1e-5f);
        float sc = lpe * cm;
        float wv[4];
#pragma unroll
        for (int m = 0; m < 4; ++m) {
            float y = (z[m] - mean) * rstd * g1[m] + bb1[m];
            wv[m] = 0.5f * y * (1.0f + erff(y * 0.70710678118654752f)) * sc;
        }
        w_s[tid] = make_float4(wv[0], wv[1], wv[2], wv[3]);
        mem_s[tid] = mem;
    }
    __syncthreads();

    float a0 = 0.f, a1 = 0.f, a2 = 0.f, a3 = 0.f;
    size_t base = (size_t)b * NTOK * DIM + tid;
#pragma unroll 8
    for (int k = 0; k < NBHD; ++k) {
        float g = featf[base + (size_t)mem_s[k] * DIM];
        float4 w = w_s[k];
        a0 += w.x * g; a1 += w.y * g; a2 += w.z * g; a3 += w.w * g;
    }
    float s1 = a0 + a1 + a2 + a3;
    float s2 = a0 * a0 + a1 * a1 + a2 * a2 + a3 * a3;
#pragma unroll
    for (int off = 32; off > 0; off >>= 1) {
        s1 += __shfl_down(s1, off, 64);
        s2 += __shfl_down(s2, off, 64);
    }
    int wave = tid >> 6, lane = tid & 63;
    if (lane == 0) { red[wave] = s1; red[4 + wave] = s2; }
    __syncthreads();
    if (tid == 0) {
        float S = red[0] + red[1] + red[2] + red[3];
        float Q = red[4] + red[5] + red[6] + red[7];
        float mean = S * (1.0f / 1024.0f);
        float var = fmaxf(Q * (1.0f / 1024.0f) - mean * mean, 0.0f);
        red[8] = mean; red[9] = rsqrtf(var + 1e-5f);
    }
    __syncthreads();
    float mean = red[8], rstd = red[9];
    float acc4[4] = {a0, a1, a2, a3};
    u16* Xp = xdst + (size_t)t * 1024;
#pragma unroll
    for (int m = 0; m < 4; ++m) {
        int cc = m * 256 + tid;
        float v = (acc4[m] - mean) * rstd * norm_g[cc] + norm_b[cc];
        Xp[cc] = f2bf(v);
    }
}

__global__ __launch_bounds__(256) void gemm_inplace_kernel(
    const float* __restrict__ lin_w, const float* __restrict__ lin_b,
    float* __restrict__ out) {
    __shared__ __align__(16) u16 Bs[BLKN * BROW];
    int tile_m = blockIdx.x;
    int nblk = blockIdx.y;
    int tid = threadIdx.x;
    int wave = tid >> 6, lane = tid & 63;
    int l15 = lane & 15, quad = lane >> 4;

    const u16* Xbase = (const u16*)out;
    floatx4 acc[8][4] = {};

    for (int kk = 0; kk < 1024; kk += 32) {
        __syncthreads();
#pragma unroll
        for (int it = 0; it < 4; ++it) {
            int task = it * 256 + tid;
            int kp = task >> 6;
            int ng = task & 63;
            int k = kp * 2;
            int n0 = nblk * BLKN + ng * 4;
            float4 fa = *(const float4*)&lin_w[(size_t)(kk + k) * OUTD + n0];
            float4 fb = *(const float4*)&lin_w[(size_t)(kk + k + 1) * OUTD + n0];
            u16* bp = &Bs[(ng * 4) * BROW + k];
            *(u32*)(bp + 0 * BROW) = (u32)f2bf(fa.x) | ((u32)f2bf(fb.x) << 16);
            *(u32*)(bp + 1 * BROW) = (u32)f2bf(fa.y) | ((u32)f2bf(fb.y) << 16);
            *(u32*)(bp + 2 * BROW) = (u32)f2bf(fa.z) | ((u32)f2bf(fb.z) << 16);
            *(u32*)(bp + 3 * BROW) = (u32)f2bf(fa.w) | ((u32)f2bf(fb.w) << 16);
        }
        __syncthreads();
        bf16x8 bfrag[4];
#pragma unroll
        for (int ni = 0; ni < 4; ++ni)
            bfrag[ni] = *(const bf16x8*)&Bs[(wave * 64 + ni * 16 + l15) * BROW + quad * 8];
#pragma unroll
        for (int mi = 0; mi < 8; ++mi) {
            int row = tile_m * BLKM + mi * 16 + l15;
            bf16x8 af = *(const bf16x8*)&Xbase[(size_t)row * 1024 + kk + quad * 8];
#pragma unroll
            for (int ni = 0; ni < 4; ++ni)
                acc[mi][ni] = __builtin_amdgcn_mfma_f32_16x16x32_bf16(
                    af, bfrag[ni], acc[mi][ni], 0, 0, 0);
        }
    }
    __syncthreads();
#pragma unroll
    for (int mi = 0; mi < 8; ++mi)
#pragma unroll
        for (int ni = 0; ni < 4; ++ni) {
            int col = nblk * BLKN + wave * 64 + ni * 16 + l15;
            float bias = lin_b[col];
#pragma unroll
            for (int reg = 0; reg < 4; ++reg) {
                int row = tile_m * BLKM + mi * 16 + quad * 4 + reg;
                out[(size_t)row * OUTD + col] = acc[mi][ni][reg] + bias;
            }
        }
}

extern "C" void kernel_launch(void* const* d_in, const int* in_sizes, int n_in,
                              void* d_out, int out_size, void* d_ws, size_t ws_size,
                              hipStream_t stream) {
    const float* feat     = (const float*)d_in[1];
    const int* member_idx = (const int*)d_in[2];
    const float* cmask    = (const float*)d_in[3];
    const float* lprob    = (const float*)d_in[4];
    const int* pe_idx     = (const int*)d_in[6];
    const float* pre_table= (const float*)d_in[8];
    const float* w1       = (const float*)d_in[9];
    const float* b1       = (const float*)d_in[10];
    const float* g1       = (const float*)d_in[11];
    const float* bb1      = (const float*)d_in[12];
    const float* norm_g   = (const float*)d_in[13];
    const float* norm_b   = (const float*)d_in[14];
    const float* lin_w    = (const float*)d_in[15];
    const float* lin_b    = (const float*)d_in[16];

    float* pos_out = (float*)d_out;
    float* out     = pos_out + POSN;

    if (ws_size >= WS_NEED) {
        char* ws = (char*)d_ws;
        u16* featb = (u16*)ws;
        u16* xws   = (u16*)(ws + FEATB_BYTES);
        u16* linT  = (u16*)(ws + FEATB_BYTES + XWS_BYTES);
        u64* slots = (u64*)(ws + FEATB_BYTES + XWS_BYTES + LINT_BYTES);
        u32* hist  = (u32*)(ws + FEATB_BYTES + XWS_BYTES + LINT_BYTES + KEYS_BYTES);
        u32* base  = hist + NB * NBKT;
        u32* curs  = base + NB * NBKT;
        // wt table (TABLE x 4 f32 = 64 KB) lives at the head of the `out`
        // region: written by linT_cvt, read by token_v5, overwritten by gemm.
        float* wtbuf = out;

        feat_cvt_kernel<<<12544, 256, 0, stream>>>(feat, featb);
        linT_cvt_kernel<<<dim3(16, 8), 256, 0, stream>>>(
            lin_w, linT, hist, pre_table, w1, b1, g1, bb1, wtbuf);
        hist_kernel<<<(NB * NTOK) / 256, 256, 0, stream>>>(lprob, hist);
        prefix_kernel<<<NB, 1024, 0, stream>>>(hist, base, curs);
        scatter_kernel<<<(NB * NTOK) / 256, 256, 0, stream>>>(lprob, curs, slots);
        rank_finalize_kernel<<<(NB * NTOK) / 256, 256, 0, stream>>>(
            lprob, hist, base, slots, pos_out);
        token_v5_kernel<<<(NB * KEEPN) / 4, 256, 0, stream>>>(
            pos_out, xws, member_idx, pe_idx, cmask, lprob, featb,
            wtbuf, norm_g, norm_b);
        gemm_tile_kernel<<<392, 256, 0, stream>>>(xws, linT, lin_b, out);
    } else {
        u64* keys = (u64*)out;
        u32* part = (u32*)((char*)out + 401408);

        key_kernel<<<(NB * NTOK) / 256, 256, 0, stream>>>(lprob, keys);
        partial_rank_kernel<<<dim3(49, NB, 4), 256, 0, stream>>>(keys, part);
        finalize_kernel<<<dim3(49, NB), 256, 0, stream>>>(part, pos_out);
        token_fb_kernel<<<NB * KEEPN, 256, 0, stream>>>(
            pos_out, (u16*)out, member_idx, pe_idx, cmask, lprob, feat,
            pre_table, w1, b1, g1, bb1, norm_g, norm_b);
        gemm_inplace_kernel<<<dim3(98, 2), 256, 0, stream>>>(lin_w, lin_b, out);
    }
}

// Round 4
// 235.847 us; speedup vs baseline: 1.3778x; 1.0217x over previous
//
#include <hip/hip_runtime.h>

typedef unsigned short u16;
typedef unsigned int u32;
typedef unsigned long long u64;

#define NB 4
#define NTOK 12544
#define NBHD 48
#define DIM 256
#define OUTD 512
#define KEEPN 3136
#define SAMPLEN 2352
#define RESN 784
#define GW 112
#define TABLE 4096
#define POSN (NB * KEEPN * 2)   // 25088 floats
#define QTR (NTOK / 4)          // 3136
#define NBKT 16384

// fallback in-place GEMM tiling
#define BLKM 128
#define BLKN 256
#define BROW 40

// ws fast-path layout (bytes)
#define FEATB_BYTES (25690112ull)                 // 4*12544*256*2
#define XWS_BYTES   (25690112ull)                 // 12544*1024*2
#define LINT_BYTES  (1048576ull)                  // 512*1024*2
#define KEYS_BYTES  (401408ull)                   // slots: 4*12544*8
#define PART_BYTES  (802816ull)                   // hist+base+cursor: 786432 used
#define WS_NEED (FEATB_BYTES + XWS_BYTES + LINT_BYTES + KEYS_BYTES + PART_BYTES)

__device__ __forceinline__ float bf2f(u16 u) {
    union { u32 i; float f; } v; v.i = ((u32)u) << 16; return v.f;
}
__device__ __forceinline__ float asf(u32 u) {
    union { u32 i; float f; } v; v.i = u; return v.f;
}
__device__ __forceinline__ u16 f2bf(float f) {
    union { u32 i; float f; } v; v.f = f;
    return (u16)((v.i + 0x7FFFu + ((v.i >> 16) & 1u)) >> 16);
}

typedef __bf16 bf16x8 __attribute__((ext_vector_type(8)));
typedef float floatx4 __attribute__((ext_vector_type(4)));
typedef float floatx2 __attribute__((ext_vector_type(2)));

// final_prob, bit-exact vs reference f32 arithmetic
__device__ __forceinline__ float make_f(float lp, int n) {
    int i = n / GW, j = n % GW;
    float f = lp * 4.0f;
    if (((i | j) & 1) == 0) f = 1.0f + f;        // grid_prob (stride 2)
    if (((i | j) & 3) == 0) f = f + (-100.0f);   // reserve penalty (stride 4)
    return f;
}
// key: descending order == top_k order; ties -> lower n first
__device__ __forceinline__ u64 f_to_key(float f, int n) {
    union { float f; u32 u; } v; v.f = f;
    u32 m = (v.u & 0x80000000u) ? ~v.u : (v.u | 0x80000000u);
    return (((u64)m) << 32) | (u64)(0xFFFFFFFFu - (u32)n);
}
__device__ __forceinline__ int f_to_bucket(float f) {
    int b = (int)floorf(f * 3276.8f);            // monotone: [0,5) -> [0,16384)
    return b < 0 ? 0 : (b > NBKT - 1 ? NBKT - 1 : b);
}

// ---- fused prep: blocks 0..127 convert+transpose lin_w -> linT, zero hist,
// ---- precompute wt table; blocks 128..12671 convert feat f32 -> bf16.
__global__ __launch_bounds__(256) void prep_kernel(
    const float* __restrict__ feat, u16* __restrict__ featb,
    const float* __restrict__ lin_w, u16* __restrict__ linT,
    u32* __restrict__ hist,
    const float* __restrict__ pre_table, const float* __restrict__ w1,
    const float* __restrict__ b1, const float* __restrict__ g1,
    const float* __restrict__ bb1, float* __restrict__ wt) {
    __shared__ u16 T[64 * 65];
    int bid = blockIdx.x;
    int t = threadIdx.x;
    if (bid >= 128) {
        // feat role
        int ft = (bid - 128) * 256 + t;
        float4 v = ((const float4*)feat)[ft];
        u64 w = (u64)f2bf(v.x) | ((u64)f2bf(v.y) << 16) |
                ((u64)f2bf(v.z) << 32) | ((u64)f2bf(v.w) << 48);
        ((u64*)featb)[ft] = w;
        return;
    }
    int bx = bid & 15, by = bid >> 4;
    int k0 = bx * 64, n0 = by * 64;
    // fused hist zeroing: 128 blocks x 512 entries = 65536
    hist[bid * 512 + t] = 0;
    hist[bid * 512 + 256 + t] = 0;
    // fused wt precompute: 128 blocks x 32 rows = TABLE rows
    int gid = bid * 256 + t;
    if (gid < TABLE) {
        float z[4];
#pragma unroll
        for (int m = 0; m < 4; ++m) {
            float acc = b1[m];
#pragma unroll
            for (int d = 0; d < 5; ++d) acc += pre_table[gid * 5 + d] * w1[d * 4 + m];
            z[m] = acc;
        }
        float mean = (z[0] + z[1] + z[2] + z[3]) * 0.25f;
        float var = 0.0f;
#pragma unroll
        for (int m = 0; m < 4; ++m) { float d = z[m] - mean; var += d * d; }
        float rstd = rsqrtf(var * 0.25f + 1e-5f);
        float wv[4];
#pragma unroll
        for (int m = 0; m < 4; ++m) {
            float y = (z[m] - mean) * rstd * g1[m] + bb1[m];
            wv[m] = 0.5f * y * (1.0f + erff(y * 0.70710678118654752f));
        }
        *(float4*)&wt[gid * 4] = make_float4(wv[0], wv[1], wv[2], wv[3]);
    }
    int r = t >> 2, c4 = (t & 3) * 16;
#pragma unroll
    for (int i = 0; i < 4; ++i) {
        float4 v = *(const float4*)&lin_w[(size_t)(k0 + r) * OUTD + n0 + c4 + i * 4];
        T[(c4 + i * 4 + 0) * 65 + r] = f2bf(v.x);
        T[(c4 + i * 4 + 1) * 65 + r] = f2bf(v.y);
        T[(c4 + i * 4 + 2) * 65 + r] = f2bf(v.z);
        T[(c4 + i * 4 + 3) * 65 + r] = f2bf(v.w);
    }
    __syncthreads();
    int nl = t >> 2, kc = (t & 3) * 16;
    union { uint4 v[2]; u16 h[16]; } u;
#pragma unroll
    for (int i = 0; i < 16; ++i) u.h[i] = T[nl * 65 + kc + i];
    u16* dst = &linT[(size_t)(n0 + nl) * 1024 + k0 + kc];
    *(uint4*)(dst + 0) = u.v[0];
    *(uint4*)(dst + 8) = u.v[1];
}

// ================= selection: exact counting-sort top-k =====================
__global__ __launch_bounds__(256) void hist_kernel(
    const float* __restrict__ lprob, u32* __restrict__ hist) {
    int g = blockIdx.x * 256 + threadIdx.x;        // 196 blocks
    int b = g / NTOK, n = g % NTOK;
    int bkt = f_to_bucket(make_f(lprob[g], n));
    atomicAdd(&hist[b * NBKT + bkt], 1u);
}

// descending exclusive prefix: base[e] = #keys in buckets > e
__global__ __launch_bounds__(1024) void prefix_kernel(
    const u32* __restrict__ hist, u32* __restrict__ base, u32* __restrict__ cursor) {
    int b = blockIdx.x, t = threadIdx.x;
    const u32* h = hist + b * NBKT;
    u32 loc[16], own = 0;
#pragma unroll
    for (int i = 0; i < 16; ++i) { loc[i] = h[t * 16 + i]; own += loc[i]; }
    __shared__ u32 buf[2][1024];
    buf[0][t] = own;
    __syncthreads();
    int src = 0;
    for (int off = 1; off < 1024; off <<= 1) {
        u32 v = buf[src][t] + ((t + off < 1024) ? buf[src][t + off] : 0u);
        buf[src ^ 1][t] = v;
        src ^= 1;
        __syncthreads();
    }
    u32 above = buf[src][t] - own;                 // chunks strictly after t
    u32 suf = 0, bout[16];
    for (int i = 15; i >= 0; --i) { bout[i] = above + suf; suf += loc[i]; }
    u32* bb = base + b * NBKT;
    u32* cc = cursor + b * NBKT;
#pragma unroll
    for (int i = 0; i < 16; ++i) { bb[t * 16 + i] = bout[i]; cc[t * 16 + i] = bout[i]; }
}

__global__ __launch_bounds__(256) void scatter_kernel(
    const float* __restrict__ lprob, u32* __restrict__ cursor,
    u64* __restrict__ slots) {
    int g = blockIdx.x * 256 + threadIdx.x;
    int b = g / NTOK, n = g % NTOK;
    float f = make_f(lprob[g], n);
    int bkt = f_to_bucket(f);
    u32 s = atomicAdd(&cursor[b * NBKT + bkt], 1u);
    slots[b * NTOK + s] = f_to_key(f, n);
}

__global__ __launch_bounds__(256) void rank_finalize_kernel(
    const float* __restrict__ lprob, const u32* __restrict__ hist,
    const u32* __restrict__ base, const u64* __restrict__ slots,
    float* __restrict__ pos_out) {
    int g = blockIdx.x * 256 + threadIdx.x;
    int b = g / NTOK, n = g % NTOK;
    int i = n / GW, j = n % GW;
    if (((i | j) & 3) == 0) {
        // reserve token: rank >= 11760 > SAMPLEN always; fills fixed tail slot
        int r = (i >> 2) * 28 + (j >> 2);
        int slot = b * KEEPN + SAMPLEN + r;
        pos_out[slot * 2 + 0] = (float)i;
        pos_out[slot * 2 + 1] = (float)j;
        return;
    }
    float f = make_f(lprob[g], n);
    int bkt = f_to_bucket(f);
    u32 r0 = base[b * NBKT + bkt];
    if (r0 >= SAMPLEN) return;                     // whole bucket below cut
    u64 my = f_to_key(f, n);
    u32 cnt = hist[b * NBKT + bkt];
    const u64* sl = slots + b * NTOK + r0;
    u32 rank = r0;
    for (u32 s = 0; s < cnt; ++s) rank += (sl[s] > my) ? 1u : 0u;
    if (rank < SAMPLEN) {
        int slot = b * KEEPN + (int)rank;
        pos_out[slot * 2 + 0] = (float)i;
        pos_out[slot * 2 + 1] = (float)j;
    }
}

// ---- K4 v6: wave-per-token gather, readlane neighbor offsets --------------
// Address chain: moff readlane (SGPR) + loop-invariant lane*8 voffset -> no
// LDS on the address critical path. Weights stay in LDS (latency-tolerant).
__global__ __launch_bounds__(256) void token_v6_kernel(
    const float* __restrict__ pos_in, u16* __restrict__ xdst,
    const int* __restrict__ member_idx, const int* __restrict__ pe_idx,
    const float* __restrict__ cmask, const float* __restrict__ lprob,
    const u16* __restrict__ featb, const float* __restrict__ wt,
    const float* __restrict__ norm_g, const float* __restrict__ norm_b) {
    // XCD-affinity: block i -> xcd i&7 (round-robin dispatch);
    // batch b owns xcds {2b, 2b+1} so per-XCD hot set = 6.4 MB.
    int bi = blockIdx.x;                 // 3136 blocks, 4 tokens each
    int xcd = bi & 7, jj = bi >> 3;      // jj in [0,392)
    int b = xcd >> 1;
    int tid = threadIdx.x;
    int wave = tid >> 6, lane = tid & 63;
    int t = b * KEEPN + (xcd & 1) * 1568 + jj * 4 + wave;

    __shared__ float4 w_s[4][NBHD];

    float2 pp = *(const float2*)&pos_in[t * 2];
    int n_src = (int)pp.x * GW + (int)pp.y;

    u32 moffb = 0;                       // byte offset of neighbor row
    if (lane < NBHD) {
        int e = (b * NTOK + n_src) * NBHD + lane;
        int mem = member_idx[e];
        int pe = pe_idx[e];
        float cm = cmask[e];
        float lpe = lprob[b * NTOK + mem];
        float4 w4 = *(const float4*)&wt[pe * 4];
        float sc = lpe * cm;
        w_s[wave][lane] = make_float4(w4.x * sc, w4.y * sc, w4.z * sc, w4.w * sc);
        moffb = (u32)mem * (DIM * 2);
    }
    __syncthreads();

    // lane owns channels lane*4 .. lane*4+3
    floatx2 accA[4] = {};   // channel j -> (m0, m1)
    floatx2 accB[4] = {};   // channel j -> (m2, m3)
    const char* fb = (const char*)featb + (size_t)b * NTOK * DIM * 2;
    u32 lane8 = (u32)lane * 8;
#pragma unroll
    for (int k = 0; k < NBHD; ++k) {
        u32 mk = (u32)__builtin_amdgcn_readlane((int)moffb, k);  // SGPR, k const
        uint2 d = *(const uint2*)(fb + mk + lane8);
        float4 w = w_s[wave][k];
        floatx2 w01 = {w.x, w.y};
        floatx2 w23 = {w.z, w.w};
        float c0 = asf(d.x << 16);
        float c1 = asf(d.x & 0xFFFF0000u);
        float c2 = asf(d.y << 16);
        float c3 = asf(d.y & 0xFFFF0000u);
        floatx2 c0v = {c0, c0}, c1v = {c1, c1}, c2v = {c2, c2}, c3v = {c3, c3};
        accA[0] = __builtin_elementwise_fma(w01, c0v, accA[0]);
        accB[0] = __builtin_elementwise_fma(w23, c0v, accB[0]);
        accA[1] = __builtin_elementwise_fma(w01, c1v, accA[1]);
        accB[1] = __builtin_elementwise_fma(w23, c1v, accB[1]);
        accA[2] = __builtin_elementwise_fma(w01, c2v, accA[2]);
        accB[2] = __builtin_elementwise_fma(w23, c2v, accB[2]);
        accA[3] = __builtin_elementwise_fma(w01, c3v, accA[3]);
        accB[3] = __builtin_elementwise_fma(w23, c3v, accB[3]);
    }

    // in-wave LN over the token's 1024 values
    float s1 = 0.0f, s2 = 0.0f;
#pragma unroll
    for (int j = 0; j < 4; ++j) {
        float v0 = accA[j][0], v1 = accA[j][1], v2 = accB[j][0], v3 = accB[j][1];
        s1 += v0 + v1 + v2 + v3;
        s2 += v0 * v0 + v1 * v1 + v2 * v2 + v3 * v3;
    }
#pragma unroll
    for (int off = 32; off > 0; off >>= 1) {
        s1 += __shfl_xor(s1, off, 64);
        s2 += __shfl_xor(s2, off, 64);
    }
    float mean = s1 * (1.0f / 1024.0f);
    float var = fmaxf(s2 * (1.0f / 1024.0f) - mean * mean, 0.0f);
    float rstd = rsqrtf(var + 1e-5f);

    u16* Xp = xdst + (size_t)t * 1024;
#pragma unroll
    for (int m = 0; m < 4; ++m) {
        int cc = m * 256 + lane * 4;
        float4 g4 = *(const float4*)&norm_g[cc];
        float4 b4 = *(const float4*)&norm_b[cc];
        float v0 = (m == 0) ? accA[0][0] : (m == 1) ? accA[0][1]
                 : (m == 2) ? accB[0][0] : accB[0][1];
        float v1 = (m == 0) ? accA[1][0] : (m == 1) ? accA[1][1]
                 : (m == 2) ? accB[1][0] : accB[1][1];
        float v2 = (m == 0) ? accA[2][0] : (m == 1) ? accA[2][1]
                 : (m == 2) ? accB[2][0] : accB[2][1];
        float v3 = (m == 0) ? accA[3][0] : (m == 1) ? accA[3][1]
                 : (m == 2) ? accB[3][0] : accB[3][1];
        u16 h0 = f2bf((v0 - mean) * rstd * g4.x + b4.x);
        u16 h1 = f2bf((v1 - mean) * rstd * g4.y + b4.y);
        u16 h2 = f2bf((v2 - mean) * rstd * g4.z + b4.z);
        u16 h3 = f2bf((v3 - mean) * rstd * g4.w + b4.w);
        u64 w = (u64)h0 | ((u64)h1 << 16) | ((u64)h2 << 32) | ((u64)h3 << 48);
        *(u64*)(Xp + cc) = w;
    }
}

// ---- K5 v5: 128x128 LDS-tiled GEMM, chunked XCD remap, 2-phase prefetch ---
#define GROW 40   // padded LDS row stride (halves)
__global__ __launch_bounds__(256) void gemm_tile_kernel(
    const u16* __restrict__ xws, const u16* __restrict__ linT,
    const float* __restrict__ lin_b, float* __restrict__ out) {
    __shared__ __align__(16) u16 As[128 * GROW];    // 10.2 KB
    __shared__ __align__(16) u16 Bs[128 * GROW];    // 10.2 KB
    // chunked XCD-affine remap: each XCD owns 49 contiguous tiles, n-fastest,
    // so its A-row band (~3.2 MB) streams through its own L2 exactly once.
    int bid = blockIdx.x;                // 392 = 98m x 4n tiles
    int xcd = bid & 7, kk8 = bid >> 3;   // kk8 in [0,49)
    int tile = xcd * 49 + kk8;
    int m0 = (tile >> 2) * 128, n0 = (tile & 3) * 128;

    int tid = threadIdx.x;
    int wave = tid >> 6, lane = tid & 63;
    int l15 = lane & 15, quad = lane >> 4;
    int wm = wave >> 1, wn = wave & 1;
    int sr = tid >> 2, sk = (tid & 3) * 8;          // 64 rows x 4 chunks per pass

    const u16* Ap0 = xws + (size_t)(m0 + sr) * 1024 + sk;
    const u16* Ap1 = Ap0 + (size_t)64 * 1024;
    const u16* Bp0 = linT + (size_t)(n0 + sr) * 1024 + sk;
    const u16* Bp1 = Bp0 + (size_t)64 * 1024;

    // prologue: stage tile 0 in registers
    uint4 a0 = *(const uint4*)(Ap0);
    uint4 a1 = *(const uint4*)(Ap1);
    uint4 b0 = *(const uint4*)(Bp0);
    uint4 b1 = *(const uint4*)(Bp1);

    floatx4 acc[4][4] = {};
    for (int kk = 0; kk < 1024; kk += 32) {
        __syncthreads();                  // prev tile's LDS reads done
        *(uint4*)&As[sr * GROW + sk] = a0;
        *(uint4*)&As[(64 + sr) * GROW + sk] = a1;
        *(uint4*)&Bs[sr * GROW + sk] = b0;
        *(uint4*)&Bs[(64 + sr) * GROW + sk] = b1;
        __syncthreads();
        if (kk + 32 < 1024) {             // issue next-tile loads before MFMA:
            a0 = *(const uint4*)(Ap0 + kk + 32);   // HBM latency hides under
            a1 = *(const uint4*)(Ap1 + kk + 32);   // the ds_read+MFMA cluster
            b0 = *(const uint4*)(Bp0 + kk + 32);
            b1 = *(const uint4*)(Bp1 + kk + 32);
        }
        bf16x8 af[4], bfv[4];
#pragma unroll
        for (int mi = 0; mi < 4; ++mi)
            af[mi] = *(const bf16x8*)&As[(wm * 64 + mi * 16 + l15) * GROW + quad * 8];
#pragma unroll
        for (int ni = 0; ni < 4; ++ni)
            bfv[ni] = *(const bf16x8*)&Bs[(wn * 64 + ni * 16 + l15) * GROW + quad * 8];
#pragma unroll
        for (int mi = 0; mi < 4; ++mi)
#pragma unroll
            for (int ni = 0; ni < 4; ++ni)
                acc[mi][ni] = __builtin_amdgcn_mfma_f32_16x16x32_bf16(
                    af[mi], bfv[ni], acc[mi][ni], 0, 0, 0);
    }
#pragma unroll
    for (int ni = 0; ni < 4; ++ni) {
        int col = n0 + wn * 64 + ni * 16 + l15;
        float bias = lin_b[col];
#pragma unroll
        for (int mi = 0; mi < 4; ++mi)
#pragma unroll
            for (int reg = 0; reg < 4; ++reg) {
                int row = m0 + wm * 64 + mi * 16 + quad * 4 + reg;
                out[(size_t)row * OUTD + col] = acc[mi][ni][reg] + bias;
            }
    }
}

// ---- fallback kernels (zero-workspace, round-3 proven) --------------------
__global__ __launch_bounds__(256) void key_kernel(
    const float* __restrict__ lprob, u64* __restrict__ keys) {
    int g = blockIdx.x * 256 + threadIdx.x;
    int n = g % NTOK;
    keys[g] = f_to_key(make_f(lprob[g], n), n);
}

__global__ __launch_bounds__(256) void partial_rank_kernel(
    const u64* __restrict__ keys, u32* __restrict__ part) {
    int b = blockIdx.y, z = blockIdx.z;
    int n = blockIdx.x * 256 + threadIdx.x;
    u64 my = keys[b * NTOK + n];
    const u64* kb = keys + b * NTOK + z * QTR;
    u32 cnt = 0;
    for (int t = 0; t < QTR; t += 8) {
#pragma unroll
        for (int j = 0; j < 8; ++j) cnt += (kb[t + j] > my) ? 1u : 0u;
    }
    part[(z * NB + b) * NTOK + n] = cnt;
}

__global__ __launch_bounds__(256) void finalize_kernel(
    const u32* __restrict__ part, float* __restrict__ pos_out) {
    int b = blockIdx.y;
    int n = blockIdx.x * 256 + threadIdx.x;
    int g = b * NTOK + n;
    u32 rank = part[g] + part[(NB + b) * NTOK + n] +
               part[(2 * NB + b) * NTOK + n] + part[(3 * NB + b) * NTOK + n];
    int i = n / GW, j = n % GW;
    if (rank < SAMPLEN) {
        int slot = b * KEEPN + (int)rank;
        pos_out[slot * 2 + 0] = (float)i;
        pos_out[slot * 2 + 1] = (float)j;
    }
    if (((i | j) & 3) == 0) {
        int r = (i >> 2) * 28 + (j >> 2);
        int slot = b * KEEPN + SAMPLEN + r;
        pos_out[slot * 2 + 0] = (float)i;
        pos_out[slot * 2 + 1] = (float)j;
    }
}

__global__ __launch_bounds__(256) void token_fb_kernel(
    const float* __restrict__ pos_in, u16* __restrict__ xdst,
    const int* __restrict__ member_idx, const int* __restrict__ pe_idx,
    const float* __restrict__ cmask, const float* __restrict__ lprob,
    const float* __restrict__ featf, const float* __restrict__ pre_table,
    const float* __restrict__ w1, const float* __restrict__ b1,
    const float* __restrict__ g1, const float* __restrict__ bb1,
    const float* __restrict__ norm_g, const float* __restrict__ norm_b) {
    int t = blockIdx.x;
    int b = t / KEEPN;
    int tid = threadIdx.x;
    __shared__ int mem_s[NBHD];
    __shared__ float4 w_s[NBHD];
    __shared__ float red[10];

    int n_src = (int)pos_in[t * 2 + 0] * GW + (int)pos_in[t * 2 + 1];

    if (tid < NBHD) {
        int e = (b * NTOK + n_src) * NBHD + tid;
        int mem = member_idx[e];
        int pe = pe_idx[e];
        float cm = cmask[e];
        float lpe = lprob[b * NTOK + mem];
        float z[4];
#pragma unroll
        for (int m = 0; m < 4; ++m) {
            float acc = b1[m];
#pragma unroll
            for (int d = 0; d < 5; ++d) acc += pre_table[pe * 5 + d] * w1[d * 4 + m];
            z[m] = acc;
        }
        float mean = (z[0] + z[1] + z[2] + z[3]) * 0.25f;
        float var = 0.0f;
#pragma unroll
        for (int m = 0; m < 4; ++m) { float d = z[m] - mean; var += d * d; }
        float rstd = rsqrtf(var * 0.25f + 1e-5f);
        float sc = lpe * cm;
        float wv[4];
#pragma unroll
        for (int m = 0; m < 4; ++m) {
            float y = (z[m] - mean) * rstd * g1[m] + bb1[m];
            wv[m] = 0.5f * y * (1.0f + erff(y * 0.70710678118654752f)) * sc;
        }
        w_s[tid] = make_float4(wv[0], wv[1], wv[2], wv[3]);
        mem_s[tid] = mem;
    }
    __syncthreads();

    float a0 = 0.f, a1 = 0.f, a2 = 0.f, a3 = 0.f;
    size_t base = (size_t)b * NTOK * DIM + tid;
#pragma unroll 8
    for (int k = 0; k < NBHD; ++k) {
        float g = featf[base + (size_t)mem_s[k] * DIM];
        float4 w = w_s[k];
        a0 += w.x * g; a1 += w.y * g; a2 += w.z * g; a3 += w.w * g;
    }
    float s1 = a0 + a1 + a2 + a3;
    float s2 = a0 * a0 + a1 * a1 + a2 * a2 + a3 * a3;
#pragma unroll
    for (int off = 32; off > 0; off >>= 1) {
        s1 += __shfl_down(s1, off, 64);
        s2 += __shfl_down(s2, off, 64);
    }
    int wave = tid >> 6, lane = tid & 63;
    if (lane == 0) { red[wave] = s1; red[4 + wave] = s2; }
    __syncthreads();
    if (tid == 0) {
        float S = red[0] + red[1] + red[2] + red[3];
        float Q = red[4] + red[5] + red[6] + red[7];
        float mean = S * (1.0f / 1024.0f);
        float var = fmaxf(Q * (1.0f / 1024.0f) - mean * mean, 0.0f);
        red[8] = mean; red[9] = rsqrtf(var + 1e-5f);
    }
    __syncthreads();
    float mean = red[8], rstd = red[9];
    float acc4[4] = {a0, a1, a2, a3};
    u16* Xp = xdst + (size_t)t * 1024;
#pragma unroll
    for (int m = 0; m < 4; ++m) {
        int cc = m * 256 + tid;
        float v = (acc4[m] - mean) * rstd * norm_g[cc] + norm_b[cc];
        Xp[cc] = f2bf(v);
    }
}

__global__ __launch_bounds__(256) void gemm_inplace_kernel(
    const float* __restrict__ lin_w, const float* __restrict__ lin_b,
    float* __restrict__ out) {
    __shared__ __align__(16) u16 Bs[BLKN * BROW];
    int tile_m = blockIdx.x;
    int nblk = blockIdx.y;
    int tid = threadIdx.x;
    int wave = tid >> 6, lane = tid & 63;
    int l15 = lane & 15, quad = lane >> 4;

    const u16* Xbase = (const u16*)out;
    floatx4 acc[8][4] = {};

    for (int kk = 0; kk < 1024; kk += 32) {
        __syncthreads();
#pragma unroll
        for (int it = 0; it < 4; ++it) {
            int task = it * 256 + tid;
            int kp = task >> 6;
            int ng = task & 63;
            int k = kp * 2;
            int n0 = nblk * BLKN + ng * 4;
            float4 fa = *(const float4*)&lin_w[(size_t)(kk + k) * OUTD + n0];
            float4 fb = *(const float4*)&lin_w[(size_t)(kk + k + 1) * OUTD + n0];
            u16* bp = &Bs[(ng * 4) * BROW + k];
            *(u32*)(bp + 0 * BROW) = (u32)f2bf(fa.x) | ((u32)f2bf(fb.x) << 16);
            *(u32*)(bp + 1 * BROW) = (u32)f2bf(fa.y) | ((u32)f2bf(fb.y) << 16);
            *(u32*)(bp + 2 * BROW) = (u32)f2bf(fa.z) | ((u32)f2bf(fb.z) << 16);
            *(u32*)(bp + 3 * BROW) = (u32)f2bf(fa.w) | ((u32)f2bf(fb.w) << 16);
        }
        __syncthreads();
        bf16x8 bfrag[4];
#pragma unroll
        for (int ni = 0; ni < 4; ++ni)
            bfrag[ni] = *(const bf16x8*)&Bs[(wave * 64 + ni * 16 + l15) * BROW + quad * 8];
#pragma unroll
        for (int mi = 0; mi < 8; ++mi) {
            int row = tile_m * BLKM + mi * 16 + l15;
            bf16x8 af = *(const bf16x8*)&Xbase[(size_t)row * 1024 + kk + quad * 8];
#pragma unroll
            for (int ni = 0; ni < 4; ++ni)
                acc[mi][ni] = __builtin_amdgcn_mfma_f32_16x16x32_bf16(
                    af, bfrag[ni], acc[mi][ni], 0, 0, 0);
        }
    }
    __syncthreads();
#pragma unroll
    for (int mi = 0; mi < 8; ++mi)
#pragma unroll
        for (int ni = 0; ni < 4; ++ni) {
            int col = nblk * BLKN + wave * 64 + ni * 16 + l15;
            float bias = lin_b[col];
#pragma unroll
            for (int reg = 0; reg < 4; ++reg) {
                int row = tile_m * BLKM + mi * 16 + quad * 4 + reg;
                out[(size_t)row * OUTD + col] = acc[mi][ni][reg] + bias;
            }
        }
}

extern "C" void kernel_launch(void* const* d_in, const int* in_sizes, int n_in,
                              void* d_out, int out_size, void* d_ws, size_t ws_size,
                              hipStream_t stream) {
    const float* feat     = (const float*)d_in[1];
    const int* member_idx = (const int*)d_in[2];
    const float* cmask    = (const float*)d_in[3];
    const float* lprob    = (const float*)d_in[4];
    const int* pe_idx     = (const int*)d_in[6];
    const float* pre_table= (const float*)d_in[8];
    const float* w1       = (const float*)d_in[9];
    const float* b1       = (const float*)d_in[10];
    const float* g1       = (const float*)d_in[11];
    const float* bb1      = (const float*)d_in[12];
    const float* norm_g   = (const float*)d_in[13];
    const float* norm_b   = (const float*)d_in[14];
    const float* lin_w    = (const float*)d_in[15];
    const float* lin_b    = (const float*)d_in[16];

    float* pos_out = (float*)d_out;
    float* out     = pos_out + POSN;

    if (ws_size >= WS_NEED) {
        char* ws = (char*)d_ws;
        u16* featb = (u16*)ws;
        u16* xws   = (u16*)(ws + FEATB_BYTES);
        u16* linT  = (u16*)(ws + FEATB_BYTES + XWS_BYTES);
        u64* slots = (u64*)(ws + FEATB_BYTES + XWS_BYTES + LINT_BYTES);
        u32* hist  = (u32*)(ws + FEATB_BYTES + XWS_BYTES + LINT_BYTES + KEYS_BYTES);
        u32* base  = hist + NB * NBKT;
        u32* curs  = base + NB * NBKT;
        // wt table (TABLE x 4 f32 = 64 KB) lives at the head of the `out`
        // region: written by prep, read by token_v6, overwritten by gemm.
        float* wtbuf = out;

        prep_kernel<<<12672, 256, 0, stream>>>(
            feat, featb, lin_w, linT, hist, pre_table, w1, b1, g1, bb1, wtbuf);
        hist_kernel<<<(NB * NTOK) / 256, 256, 0, stream>>>(lprob, hist);
        prefix_kernel<<<NB, 1024, 0, stream>>>(hist, base, curs);
        scatter_kernel<<<(NB * NTOK) / 256, 256, 0, stream>>>(lprob, curs, slots);
        rank_finalize_kernel<<<(NB * NTOK) / 256, 256, 0, stream>>>(
            lprob, hist, base, slots, pos_out);
        token_v6_kernel<<<(NB * KEEPN) / 4, 256, 0, stream>>>(
            pos_out, xws, member_idx, pe_idx, cmask, lprob, featb,
            wtbuf, norm_g, norm_b);
        gemm_tile_kernel<<<392, 256, 0, stream>>>(xws, linT, lin_b, out);
    } else {
        u64* keys = (u64*)out;
        u32* part = (u32*)((char*)out + 401408);

        key_kernel<<<(NB * NTOK) / 256, 256, 0, stream>>>(lprob, keys);
        partial_rank_kernel<<<dim3(49, NB, 4), 256, 0, stream>>>(keys, part);
        finalize_kernel<<<dim3(49, NB), 256, 0, stream>>>(part, pos_out);
        token_fb_kernel<<<NB * KEEPN, 256, 0, stream>>>(
            pos_out, (u16*)out, member_idx, pe_idx, cmask, lprob, feat,
            pre_table, w1, b1, g1, bb1, norm_g, norm_b);
        gemm_inplace_kernel<<<dim3(98, 2), 256, 0, stream>>>(lin_w, lin_b, out);
    }
}

// Round 5
// 235.185 us; speedup vs baseline: 1.3817x; 1.0028x over previous
//
#include <hip/hip_runtime.h>

typedef unsigned short u16;
typedef unsigned int u32;
typedef unsigned long long u64;

#define NB 4
#define NTOK 12544
#define NBHD 48
#define DIM 256
#define OUTD 512
#define KEEPN 3136
#define SAMPLEN 2352
#define RESN 784
#define GW 112
#define TABLE 4096
#define POSN (NB * KEEPN * 2)   // 25088 floats
#define QTR (NTOK / 4)          // 3136
#define NBKT 16384

// fallback in-place GEMM tiling
#define BLKM 128
#define BLKN 256
#define BROW 40

// ws fast-path layout (bytes)
#define FEATB_BYTES (25690112ull)                 // 4*12544*256*2
#define XWS_BYTES   (25690112ull)                 // 12544*1024*2
#define LINT_BYTES  (1048576ull)                  // 512*1024*2
#define KEYS_BYTES  (401408ull)                   // slots: 4*12544*8
#define PART_BYTES  (802816ull)                   // hist+base+cursor: 786432 used
#define WS_NEED (FEATB_BYTES + XWS_BYTES + LINT_BYTES + KEYS_BYTES + PART_BYTES)

__device__ __forceinline__ float bf2f(u16 u) {
    union { u32 i; float f; } v; v.i = ((u32)u) << 16; return v.f;
}
__device__ __forceinline__ float asf(u32 u) {
    union { u32 i; float f; } v; v.i = u; return v.f;
}
__device__ __forceinline__ u16 f2bf(float f) {
    union { u32 i; float f; } v; v.f = f;
    return (u16)((v.i + 0x7FFFu + ((v.i >> 16) & 1u)) >> 16);
}

typedef __bf16 bf16x8 __attribute__((ext_vector_type(8)));
typedef float floatx4 __attribute__((ext_vector_type(4)));
typedef float floatx2 __attribute__((ext_vector_type(2)));

// final_prob, bit-exact vs reference f32 arithmetic
__device__ __forceinline__ float make_f(float lp, int n) {
    int i = n / GW, j = n % GW;
    float f = lp * 4.0f;
    if (((i | j) & 1) == 0) f = 1.0f + f;        // grid_prob (stride 2)
    if (((i | j) & 3) == 0) f = f + (-100.0f);   // reserve penalty (stride 4)
    return f;
}
// key: descending order == top_k order; ties -> lower n first
__device__ __forceinline__ u64 f_to_key(float f, int n) {
    union { float f; u32 u; } v; v.f = f;
    u32 m = (v.u & 0x80000000u) ? ~v.u : (v.u | 0x80000000u);
    return (((u64)m) << 32) | (u64)(0xFFFFFFFFu - (u32)n);
}
__device__ __forceinline__ int f_to_bucket(float f) {
    int b = (int)floorf(f * 3276.8f);            // monotone: [0,5) -> [0,16384)
    return b < 0 ? 0 : (b > NBKT - 1 ? NBKT - 1 : b);
}

// ---- fused prep: blocks 0..127 convert+transpose lin_w -> linT, zero hist,
// ---- precompute wt table; blocks 128..12671 convert feat f32 -> bf16.
__global__ __launch_bounds__(256) void prep_kernel(
    const float* __restrict__ feat, u16* __restrict__ featb,
    const float* __restrict__ lin_w, u16* __restrict__ linT,
    u32* __restrict__ hist,
    const float* __restrict__ pre_table, const float* __restrict__ w1,
    const float* __restrict__ b1, const float* __restrict__ g1,
    const float* __restrict__ bb1, float* __restrict__ wt) {
    __shared__ u16 T[64 * 65];
    int bid = blockIdx.x;
    int t = threadIdx.x;
    if (bid >= 128) {
        // feat role
        int ft = (bid - 128) * 256 + t;
        float4 v = ((const float4*)feat)[ft];
        u64 w = (u64)f2bf(v.x) | ((u64)f2bf(v.y) << 16) |
                ((u64)f2bf(v.z) << 32) | ((u64)f2bf(v.w) << 48);
        ((u64*)featb)[ft] = w;
        return;
    }
    int bx = bid & 15, by = bid >> 4;
    int k0 = bx * 64, n0 = by * 64;
    // fused hist zeroing: 128 blocks x 512 entries = 65536
    hist[bid * 512 + t] = 0;
    hist[bid * 512 + 256 + t] = 0;
    // fused wt precompute: 128 blocks x 32 rows = TABLE rows
    int gid = bid * 256 + t;
    if (gid < TABLE) {
        float z[4];
#pragma unroll
        for (int m = 0; m < 4; ++m) {
            float acc = b1[m];
#pragma unroll
            for (int d = 0; d < 5; ++d) acc += pre_table[gid * 5 + d] * w1[d * 4 + m];
            z[m] = acc;
        }
        float mean = (z[0] + z[1] + z[2] + z[3]) * 0.25f;
        float var = 0.0f;
#pragma unroll
        for (int m = 0; m < 4; ++m) { float d = z[m] - mean; var += d * d; }
        float rstd = rsqrtf(var * 0.25f + 1e-5f);
        float wv[4];
#pragma unroll
        for (int m = 0; m < 4; ++m) {
            float y = (z[m] - mean) * rstd * g1[m] + bb1[m];
            wv[m] = 0.5f * y * (1.0f + erff(y * 0.70710678118654752f));
        }
        *(float4*)&wt[gid * 4] = make_float4(wv[0], wv[1], wv[2], wv[3]);
    }
    int r = t >> 2, c4 = (t & 3) * 16;
#pragma unroll
    for (int i = 0; i < 4; ++i) {
        float4 v = *(const float4*)&lin_w[(size_t)(k0 + r) * OUTD + n0 + c4 + i * 4];
        T[(c4 + i * 4 + 0) * 65 + r] = f2bf(v.x);
        T[(c4 + i * 4 + 1) * 65 + r] = f2bf(v.y);
        T[(c4 + i * 4 + 2) * 65 + r] = f2bf(v.z);
        T[(c4 + i * 4 + 3) * 65 + r] = f2bf(v.w);
    }
    __syncthreads();
    int nl = t >> 2, kc = (t & 3) * 16;
    union { uint4 v[2]; u16 h[16]; } u;
#pragma unroll
    for (int i = 0; i < 16; ++i) u.h[i] = T[nl * 65 + kc + i];
    u16* dst = &linT[(size_t)(n0 + nl) * 1024 + k0 + kc];
    *(uint4*)(dst + 0) = u.v[0];
    *(uint4*)(dst + 8) = u.v[1];
}

// ================= selection: exact counting-sort top-k =====================
__global__ __launch_bounds__(256) void hist_kernel(
    const float* __restrict__ lprob, u32* __restrict__ hist) {
    int g = blockIdx.x * 256 + threadIdx.x;        // 196 blocks
    int b = g / NTOK, n = g % NTOK;
    int bkt = f_to_bucket(make_f(lprob[g], n));
    atomicAdd(&hist[b * NBKT + bkt], 1u);
}

// descending exclusive prefix: base[e] = #keys in buckets > e
__global__ __launch_bounds__(1024) void prefix_kernel(
    const u32* __restrict__ hist, u32* __restrict__ base, u32* __restrict__ cursor) {
    int b = blockIdx.x, t = threadIdx.x;
    const u32* h = hist + b * NBKT;
    u32 loc[16], own = 0;
#pragma unroll
    for (int i = 0; i < 16; ++i) { loc[i] = h[t * 16 + i]; own += loc[i]; }
    __shared__ u32 buf[2][1024];
    buf[0][t] = own;
    __syncthreads();
    int src = 0;
    for (int off = 1; off < 1024; off <<= 1) {
        u32 v = buf[src][t] + ((t + off < 1024) ? buf[src][t + off] : 0u);
        buf[src ^ 1][t] = v;
        src ^= 1;
        __syncthreads();
    }
    u32 above = buf[src][t] - own;                 // chunks strictly after t
    u32 suf = 0, bout[16];
    for (int i = 15; i >= 0; --i) { bout[i] = above + suf; suf += loc[i]; }
    u32* bb = base + b * NBKT;
    u32* cc = cursor + b * NBKT;
#pragma unroll
    for (int i = 0; i < 16; ++i) { bb[t * 16 + i] = bout[i]; cc[t * 16 + i] = bout[i]; }
}

__global__ __launch_bounds__(256) void scatter_kernel(
    const float* __restrict__ lprob, u32* __restrict__ cursor,
    u64* __restrict__ slots) {
    int g = blockIdx.x * 256 + threadIdx.x;
    int b = g / NTOK, n = g % NTOK;
    float f = make_f(lprob[g], n);
    int bkt = f_to_bucket(f);
    u32 s = atomicAdd(&cursor[b * NBKT + bkt], 1u);
    slots[b * NTOK + s] = f_to_key(f, n);
}

__global__ __launch_bounds__(256) void rank_finalize_kernel(
    const float* __restrict__ lprob, const u32* __restrict__ hist,
    const u32* __restrict__ base, const u64* __restrict__ slots,
    float* __restrict__ pos_out) {
    int g = blockIdx.x * 256 + threadIdx.x;
    int b = g / NTOK, n = g % NTOK;
    int i = n / GW, j = n % GW;
    if (((i | j) & 3) == 0) {
        // reserve token: rank >= 11760 > SAMPLEN always; fills fixed tail slot
        int r = (i >> 2) * 28 + (j >> 2);
        int slot = b * KEEPN + SAMPLEN + r;
        pos_out[slot * 2 + 0] = (float)i;
        pos_out[slot * 2 + 1] = (float)j;
        return;
    }
    float f = make_f(lprob[g], n);
    int bkt = f_to_bucket(f);
    u32 r0 = base[b * NBKT + bkt];
    if (r0 >= SAMPLEN) return;                     // whole bucket below cut
    u64 my = f_to_key(f, n);
    u32 cnt = hist[b * NBKT + bkt];
    const u64* sl = slots + b * NTOK + r0;
    u32 rank = r0;
    for (u32 s = 0; s < cnt; ++s) rank += (sl[s] > my) ? 1u : 0u;
    if (rank < SAMPLEN) {
        int slot = b * KEEPN + (int)rank;
        pos_out[slot * 2 + 0] = (float)i;
        pos_out[slot * 2 + 1] = (float)j;
    }
}

// ---- per-token accumulate+LN+store body (v6 math, bit-identical) ----------
__device__ __forceinline__ void token_body(
    const char* fb, u32 lane8, u32 moffb, const float4* ws,
    int lane, int t, u16* __restrict__ xdst,
    const float* __restrict__ norm_g, const float* __restrict__ norm_b) {
    floatx2 accA[4] = {};   // channel j -> (m0, m1)
    floatx2 accB[4] = {};   // channel j -> (m2, m3)
#pragma unroll
    for (int k = 0; k < NBHD; ++k) {
        u32 mk = (u32)__builtin_amdgcn_readlane((int)moffb, k);  // SGPR, k const
        uint2 d = *(const uint2*)(fb + mk + lane8);
        float4 w = ws[k];
        floatx2 w01 = {w.x, w.y};
        floatx2 w23 = {w.z, w.w};
        float c0 = asf(d.x << 16);
        float c1 = asf(d.x & 0xFFFF0000u);
        float c2 = asf(d.y << 16);
        float c3 = asf(d.y & 0xFFFF0000u);
        floatx2 c0v = {c0, c0}, c1v = {c1, c1}, c2v = {c2, c2}, c3v = {c3, c3};
        accA[0] = __builtin_elementwise_fma(w01, c0v, accA[0]);
        accB[0] = __builtin_elementwise_fma(w23, c0v, accB[0]);
        accA[1] = __builtin_elementwise_fma(w01, c1v, accA[1]);
        accB[1] = __builtin_elementwise_fma(w23, c1v, accB[1]);
        accA[2] = __builtin_elementwise_fma(w01, c2v, accA[2]);
        accB[2] = __builtin_elementwise_fma(w23, c2v, accB[2]);
        accA[3] = __builtin_elementwise_fma(w01, c3v, accA[3]);
        accB[3] = __builtin_elementwise_fma(w23, c3v, accB[3]);
    }

    // in-wave LN over the token's 1024 values
    float s1 = 0.0f, s2 = 0.0f;
#pragma unroll
    for (int j = 0; j < 4; ++j) {
        float v0 = accA[j][0], v1 = accA[j][1], v2 = accB[j][0], v3 = accB[j][1];
        s1 += v0 + v1 + v2 + v3;
        s2 += v0 * v0 + v1 * v1 + v2 * v2 + v3 * v3;
    }
#pragma unroll
    for (int off = 32; off > 0; off >>= 1) {
        s1 += __shfl_xor(s1, off, 64);
        s2 += __shfl_xor(s2, off, 64);
    }
    float mean = s1 * (1.0f / 1024.0f);
    float var = fmaxf(s2 * (1.0f / 1024.0f) - mean * mean, 0.0f);
    float rstd = rsqrtf(var + 1e-5f);

    u16* Xp = xdst + (size_t)t * 1024;
#pragma unroll
    for (int m = 0; m < 4; ++m) {
        int cc = m * 256 + lane * 4;
        float4 g4 = *(const float4*)&norm_g[cc];
        float4 b4 = *(const float4*)&norm_b[cc];
        float v0 = (m == 0) ? accA[0][0] : (m == 1) ? accA[0][1]
                 : (m == 2) ? accB[0][0] : accB[0][1];
        float v1 = (m == 0) ? accA[1][0] : (m == 1) ? accA[1][1]
                 : (m == 2) ? accB[1][0] : accB[1][1];
        float v2 = (m == 0) ? accA[2][0] : (m == 1) ? accA[2][1]
                 : (m == 2) ? accB[2][0] : accB[2][1];
        float v3 = (m == 0) ? accA[3][0] : (m == 1) ? accA[3][1]
                 : (m == 2) ? accB[3][0] : accB[3][1];
        u16 h0 = f2bf((v0 - mean) * rstd * g4.x + b4.x);
        u16 h1 = f2bf((v1 - mean) * rstd * g4.y + b4.y);
        u16 h2 = f2bf((v2 - mean) * rstd * g4.z + b4.z);
        u16 h3 = f2bf((v3 - mean) * rstd * g4.w + b4.w);
        u64 w = (u64)h0 | ((u64)h1 << 16) | ((u64)h2 << 32) | ((u64)h3 << 48);
        *(u64*)(Xp + cc) = w;
    }
}

// ---- K4 v7: 2 tokens per wave, fully-resident grid (1568 blocks) ----------
// 1568 blocks <= 2048 resident capacity -> single dispatch round, no tail.
// One staging phase + one barrier covers both tokens.
__global__ __launch_bounds__(256) void token_v7_kernel(
    const float* __restrict__ pos_in, u16* __restrict__ xdst,
    const int* __restrict__ member_idx, const int* __restrict__ pe_idx,
    const float* __restrict__ cmask, const float* __restrict__ lprob,
    const u16* __restrict__ featb, const float* __restrict__ wt,
    const float* __restrict__ norm_g, const float* __restrict__ norm_b) {
    // XCD-affinity: block i -> xcd i&7 (round-robin dispatch);
    // batch b owns xcds {2b, 2b+1} so per-XCD hot set = 6.4 MB.
    int bi = blockIdx.x;                 // 1568 blocks, 8 tokens each
    int xcd = bi & 7, jj = bi >> 3;      // jj in [0,196)
    int b = xcd >> 1;
    int tid = threadIdx.x;
    int wave = tid >> 6, lane = tid & 63;
    int t0 = b * KEEPN + (xcd & 1) * 1568 + jj * 8 + wave * 2;

    __shared__ float4 w_s[4][2][NBHD];

    // pos for tokens t0, t0+1: 4 consecutive floats
    float4 pq = *(const float4*)&pos_in[t0 * 2];
    int ns0 = (int)pq.x * GW + (int)pq.y;
    int ns1 = (int)pq.z * GW + (int)pq.w;

    u32 moff0 = 0, moff1 = 0;
    if (lane < NBHD) {
        {
            int e = (b * NTOK + ns0) * NBHD + lane;
            int mem = member_idx[e];
            float sc = lprob[b * NTOK + mem] * cmask[e];
            float4 w4 = *(const float4*)&wt[pe_idx[e] * 4];
            w_s[wave][0][lane] = make_float4(w4.x * sc, w4.y * sc, w4.z * sc, w4.w * sc);
            moff0 = (u32)mem * (DIM * 2);
        }
        {
            int e = (b * NTOK + ns1) * NBHD + lane;
            int mem = member_idx[e];
            float sc = lprob[b * NTOK + mem] * cmask[e];
            float4 w4 = *(const float4*)&wt[pe_idx[e] * 4];
            w_s[wave][1][lane] = make_float4(w4.x * sc, w4.y * sc, w4.z * sc, w4.w * sc);
            moff1 = (u32)mem * (DIM * 2);
        }
    }
    __syncthreads();

    const char* fb = (const char*)featb + (size_t)b * NTOK * DIM * 2;
    u32 lane8 = (u32)lane * 8;
    token_body(fb, lane8, moff0, w_s[wave][0], lane, t0, xdst, norm_g, norm_b);
    token_body(fb, lane8, moff1, w_s[wave][1], lane, t0 + 1, xdst, norm_g, norm_b);
}

// ---- K5 v5: 128x128 LDS-tiled GEMM, chunked XCD remap, 2-phase prefetch ---
#define GROW 40   // padded LDS row stride (halves)
__global__ __launch_bounds__(256) void gemm_tile_kernel(
    const u16* __restrict__ xws, const u16* __restrict__ linT,
    const float* __restrict__ lin_b, float* __restrict__ out) {
    __shared__ __align__(16) u16 As[128 * GROW];    // 10.2 KB
    __shared__ __align__(16) u16 Bs[128 * GROW];    // 10.2 KB
    // chunked XCD-affine remap: each XCD owns 49 contiguous tiles, n-fastest,
    // so its A-row band (~3.2 MB) streams through its own L2 exactly once.
    int bid = blockIdx.x;                // 392 = 98m x 4n tiles
    int xcd = bid & 7, kk8 = bid >> 3;   // kk8 in [0,49)
    int tile = xcd * 49 + kk8;
    int m0 = (tile >> 2) * 128, n0 = (tile & 3) * 128;

    int tid = threadIdx.x;
    int wave = tid >> 6, lane = tid & 63;
    int l15 = lane & 15, quad = lane >> 4;
    int wm = wave >> 1, wn = wave & 1;
    int sr = tid >> 2, sk = (tid & 3) * 8;          // 64 rows x 4 chunks per pass

    const u16* Ap0 = xws + (size_t)(m0 + sr) * 1024 + sk;
    const u16* Ap1 = Ap0 + (size_t)64 * 1024;
    const u16* Bp0 = linT + (size_t)(n0 + sr) * 1024 + sk;
    const u16* Bp1 = Bp0 + (size_t)64 * 1024;

    // prologue: stage tile 0 in registers
    uint4 a0 = *(const uint4*)(Ap0);
    uint4 a1 = *(const uint4*)(Ap1);
    uint4 b0 = *(const uint4*)(Bp0);
    uint4 b1 = *(const uint4*)(Bp1);

    floatx4 acc[4][4] = {};
    for (int kk = 0; kk < 1024; kk += 32) {
        __syncthreads();                  // prev tile's LDS reads done
        *(uint4*)&As[sr * GROW + sk] = a0;
        *(uint4*)&As[(64 + sr) * GROW + sk] = a1;
        *(uint4*)&Bs[sr * GROW + sk] = b0;
        *(uint4*)&Bs[(64 + sr) * GROW + sk] = b1;
        __syncthreads();
        if (kk + 32 < 1024) {             // issue next-tile loads before MFMA:
            a0 = *(const uint4*)(Ap0 + kk + 32);   // HBM latency hides under
            a1 = *(const uint4*)(Ap1 + kk + 32);   // the ds_read+MFMA cluster
            b0 = *(const uint4*)(Bp0 + kk + 32);
            b1 = *(const uint4*)(Bp1 + kk + 32);
        }
        bf16x8 af[4], bfv[4];
#pragma unroll
        for (int mi = 0; mi < 4; ++mi)
            af[mi] = *(const bf16x8*)&As[(wm * 64 + mi * 16 + l15) * GROW + quad * 8];
#pragma unroll
        for (int ni = 0; ni < 4; ++ni)
            bfv[ni] = *(const bf16x8*)&Bs[(wn * 64 + ni * 16 + l15) * GROW + quad * 8];
#pragma unroll
        for (int mi = 0; mi < 4; ++mi)
#pragma unroll
            for (int ni = 0; ni < 4; ++ni)
                acc[mi][ni] = __builtin_amdgcn_mfma_f32_16x16x32_bf16(
                    af[mi], bfv[ni], acc[mi][ni], 0, 0, 0);
    }
#pragma unroll
    for (int ni = 0; ni < 4; ++ni) {
        int col = n0 + wn * 64 + ni * 16 + l15;
        float bias = lin_b[col];
#pragma unroll
        for (int mi = 0; mi < 4; ++mi)
#pragma unroll
            for (int reg = 0; reg < 4; ++reg) {
                int row = m0 + wm * 64 + mi * 16 + quad * 4 + reg;
                out[(size_t)row * OUTD + col] = acc[mi][ni][reg] + bias;
            }
    }
}

// ---- fallback kernels (zero-workspace, round-3 proven) --------------------
__global__ __launch_bounds__(256) void key_kernel(
    const float* __restrict__ lprob, u64* __restrict__ keys) {
    int g = blockIdx.x * 256 + threadIdx.x;
    int n = g % NTOK;
    keys[g] = f_to_key(make_f(lprob[g], n), n);
}

__global__ __launch_bounds__(256) void partial_rank_kernel(
    const u64* __restrict__ keys, u32* __restrict__ part) {
    int b = blockIdx.y, z = blockIdx.z;
    int n = blockIdx.x * 256 + threadIdx.x;
    u64 my = keys[b * NTOK + n];
    const u64* kb = keys + b * NTOK + z * QTR;
    u32 cnt = 0;
    for (int t = 0; t < QTR; t += 8) {
#pragma unroll
        for (int j = 0; j < 8; ++j) cnt += (kb[t + j] > my) ? 1u : 0u;
    }
    part[(z * NB + b) * NTOK + n] = cnt;
}

__global__ __launch_bounds__(256) void finalize_kernel(
    const u32* __restrict__ part, float* __restrict__ pos_out) {
    int b = blockIdx.y;
    int n = blockIdx.x * 256 + threadIdx.x;
    int g = b * NTOK + n;
    u32 rank = part[g] + part[(NB + b) * NTOK + n] +
               part[(2 * NB + b) * NTOK + n] + part[(3 * NB + b) * NTOK + n];
    int i = n / GW, j = n % GW;
    if (rank < SAMPLEN) {
        int slot = b * KEEPN + (int)rank;
        pos_out[slot * 2 + 0] = (float)i;
        pos_out[slot * 2 + 1] = (float)j;
    }
    if (((i | j) & 3) == 0) {
        int r = (i >> 2) * 28 + (j >> 2);
        int slot = b * KEEPN + SAMPLEN + r;
        pos_out[slot * 2 + 0] = (float)i;
        pos_out[slot * 2 + 1] = (float)j;
    }
}

__global__ __launch_bounds__(256) void token_fb_kernel(
    const float* __restrict__ pos_in, u16* __restrict__ xdst,
    const int* __restrict__ member_idx, const int* __restrict__ pe_idx,
    const float* __restrict__ cmask, const float* __restrict__ lprob,
    const float* __restrict__ featf, const float* __restrict__ pre_table,
    const float* __restrict__ w1, const float* __restrict__ b1,
    const float* __restrict__ g1, const float* __restrict__ bb1,
    const float* __restrict__ norm_g, const float* __restrict__ norm_b) {
    int t = blockIdx.x;
    int b = t / KEEPN;
    int tid = threadIdx.x;
    __shared__ int mem_s[NBHD];
    __shared__ float4 w_s[NBHD];
    __shared__ float red[10];

    int n_src = (int)pos_in[t * 2 + 0] * GW + (int)pos_in[t * 2 + 1];

    if (tid < NBHD) {
        int e = (b * NTOK + n_src) * NBHD + tid;
        int mem = member_idx[e];
        int pe = pe_idx[e];
        float cm = cmask[e];
        float lpe = lprob[b * NTOK + mem];
        float z[4];
#pragma unroll
        for (int m = 0; m < 4; ++m) {
            float acc = b1[m];
#pragma unroll
            for (int d = 0; d < 5; ++d) acc += pre_table[pe * 5 + d] * w1[d * 4 + m];
            z[m] = acc;
        }
        float mean = (z[0] + z[1] + z[2] + z[3]) * 0.25f;
        float var = 0.0f;
#pragma unroll
        for (int m = 0; m < 4; ++m) { float d = z[m] - mean; var += d * d; }
        float rstd = rsqrtf(var * 0.25f + 1e-5f);
        float sc = lpe * cm;
        float wv[4];
#pragma unroll
        for (int m = 0; m < 4; ++m) {
            float y = (z[m] - mean) * rstd * g1[m] + bb1[m];
            wv[m] = 0.5f * y * (1.0f + erff(y * 0.70710678118654752f)) * sc;
        }
        w_s[tid] = make_float4(wv[0], wv[1], wv[2], wv[3]);
        mem_s[tid] = mem;
    }
    __syncthreads();

    float a0 = 0.f, a1 = 0.f, a2 = 0.f, a3 = 0.f;
    size_t base = (size_t)b * NTOK * DIM + tid;
#pragma unroll 8
    for (int k = 0; k < NBHD; ++k) {
        float g = featf[base + (size_t)mem_s[k] * DIM];
        float4 w = w_s[k];
        a0 += w.x * g; a1 += w.y * g; a2 += w.z * g; a3 += w.w * g;
    }
    float s1 = a0 + a1 + a2 + a3;
    float s2 = a0 * a0 + a1 * a1 + a2 * a2 + a3 * a3;
#pragma unroll
    for (int off = 32; off > 0; off >>= 1) {
        s1 += __shfl_down(s1, off, 64);
        s2 += __shfl_down(s2, off, 64);
    }
    int wave = tid >> 6, lane = tid & 63;
    if (lane == 0) { red[wave] = s1; red[4 + wave] = s2; }
    __syncthreads();
    if (tid == 0) {
        float S = red[0] + red[1] + red[2] + red[3];
        float Q = red[4] + red[5] + red[6] + red[7];
        float mean = S * (1.0f / 1024.0f);
        float var = fmaxf(Q * (1.0f / 1024.0f) - mean * mean, 0.0f);
        red[8] = mean; red[9] = rsqrtf(var + 1e-5f);
    }
    __syncthreads();
    float mean = red[8], rstd = red[9];
    float acc4[4] = {a0, a1, a2, a3};
    u16* Xp = xdst + (size_t)t * 1024;
#pragma unroll
    for (int m = 0; m < 4; ++m) {
        int cc = m * 256 + tid;
        float v = (acc4[m] - mean) * rstd * norm_g[cc] + norm_b[cc];
        Xp[cc] = f2bf(v);
    }
}

__global__ __launch_bounds__(256) void gemm_inplace_kernel(
    const float* __restrict__ lin_w, const float* __restrict__ lin_b,
    float* __restrict__ out) {
    __shared__ __align__(16) u16 Bs[BLKN * BROW];
    int tile_m = blockIdx.x;
    int nblk = blockIdx.y;
    int tid = threadIdx.x;
    int wave = tid >> 6, lane = tid & 63;
    int l15 = lane & 15, quad = lane >> 4;

    const u16* Xbase = (const u16*)out;
    floatx4 acc[8][4] = {};

    for (int kk = 0; kk < 1024; kk += 32) {
        __syncthreads();
#pragma unroll
        for (int it = 0; it < 4; ++it) {
            int task = it * 256 + tid;
            int kp = task >> 6;
            int ng = task & 63;
            int k = kp * 2;
            int n0 = nblk * BLKN + ng * 4;
            float4 fa = *(const float4*)&lin_w[(size_t)(kk + k) * OUTD + n0];
            float4 fb = *(const float4*)&lin_w[(size_t)(kk + k + 1) * OUTD + n0];
            u16* bp = &Bs[(ng * 4) * BROW + k];
            *(u32*)(bp + 0 * BROW) = (u32)f2bf(fa.x) | ((u32)f2bf(fb.x) << 16);
            *(u32*)(bp + 1 * BROW) = (u32)f2bf(fa.y) | ((u32)f2bf(fb.y) << 16);
            *(u32*)(bp + 2 * BROW) = (u32)f2bf(fa.z) | ((u32)f2bf(fb.z) << 16);
            *(u32*)(bp + 3 * BROW) = (u32)f2bf(fa.w) | ((u32)f2bf(fb.w) << 16);
        }
        __syncthreads();
        bf16x8 bfrag[4];
#pragma unroll
        for (int ni = 0; ni < 4; ++ni)
            bfrag[ni] = *(const bf16x8*)&Bs[(wave * 64 + ni * 16 + l15) * BROW + quad * 8];
#pragma unroll
        for (int mi = 0; mi < 8; ++mi) {
            int row = tile_m * BLKM + mi * 16 + l15;
            bf16x8 af = *(const bf16x8*)&Xbase[(size_t)row * 1024 + kk + quad * 8];
#pragma unroll
            for (int ni = 0; ni < 4; ++ni)
                acc[mi][ni] = __builtin_amdgcn_mfma_f32_16x16x32_bf16(
                    af, bfrag[ni], acc[mi][ni], 0, 0, 0);
        }
    }
    __syncthreads();
#pragma unroll
    for (int mi = 0; mi < 8; ++mi)
#pragma unroll
        for (int ni = 0; ni < 4; ++ni) {
            int col = nblk * BLKN + wave * 64 + ni * 16 + l15;
            float bias = lin_b[col];
#pragma unroll
            for (int reg = 0; reg < 4; ++reg) {
                int row = tile_m * BLKM + mi * 16 + quad * 4 + reg;
                out[(size_t)row * OUTD + col] = acc[mi][ni][reg] + bias;
            }
        }
}

extern "C" void kernel_launch(void* const* d_in, const int* in_sizes, int n_in,
                              void* d_out, int out_size, void* d_ws, size_t ws_size,
                              hipStream_t stream) {
    const float* feat     = (const float*)d_in[1];
    const int* member_idx = (const int*)d_in[2];
    const float* cmask    = (const float*)d_in[3];
    const float* lprob    = (const float*)d_in[4];
    const int* pe_idx     = (const int*)d_in[6];
    const float* pre_table= (const float*)d_in[8];
    const float* w1       = (const float*)d_in[9];
    const float* b1       = (const float*)d_in[10];
    const float* g1       = (const float*)d_in[11];
    const float* bb1      = (const float*)d_in[12];
    const float* norm_g   = (const float*)d_in[13];
    const float* norm_b   = (const float*)d_in[14];
    const float* lin_w    = (const float*)d_in[15];
    const float* lin_b    = (const float*)d_in[16];

    float* pos_out = (float*)d_out;
    float* out     = pos_out + POSN;

    if (ws_size >= WS_NEED) {
        char* ws = (char*)d_ws;
        u16* featb = (u16*)ws;
        u16* xws   = (u16*)(ws + FEATB_BYTES);
        u16* linT  = (u16*)(ws + FEATB_BYTES + XWS_BYTES);
        u64* slots = (u64*)(ws + FEATB_BYTES + XWS_BYTES + LINT_BYTES);
        u32* hist  = (u32*)(ws + FEATB_BYTES + XWS_BYTES + LINT_BYTES + KEYS_BYTES);
        u32* base  = hist + NB * NBKT;
        u32* curs  = base + NB * NBKT;
        // wt table (TABLE x 4 f32 = 64 KB) lives at the head of the `out`
        // region: written by prep, read by token_v7, overwritten by gemm.
        float* wtbuf = out;

        prep_kernel<<<12672, 256, 0, stream>>>(
            feat, featb, lin_w, linT, hist, pre_table, w1, b1, g1, bb1, wtbuf);
        hist_kernel<<<(NB * NTOK) / 256, 256, 0, stream>>>(lprob, hist);
        prefix_kernel<<<NB, 1024, 0, stream>>>(hist, base, curs);
        scatter_kernel<<<(NB * NTOK) / 256, 256, 0, stream>>>(lprob, curs, slots);
        rank_finalize_kernel<<<(NB * NTOK) / 256, 256, 0, stream>>>(
            lprob, hist, base, slots, pos_out);
        token_v7_kernel<<<(NB * KEEPN) / 8, 256, 0, stream>>>(
            pos_out, xws, member_idx, pe_idx, cmask, lprob, featb,
            wtbuf, norm_g, norm_b);
        gemm_tile_kernel<<<392, 256, 0, stream>>>(xws, linT, lin_b, out);
    } else {
        u64* keys = (u64*)out;
        u32* part = (u32*)((char*)out + 401408);

        key_kernel<<<(NB * NTOK) / 256, 256, 0, stream>>>(lprob, keys);
        partial_rank_kernel<<<dim3(49, NB, 4), 256, 0, stream>>>(keys, part);
        finalize_kernel<<<dim3(49, NB), 256, 0, stream>>>(part, pos_out);
        token_fb_kernel<<<NB * KEEPN, 256, 0, stream>>>(
            pos_out, (u16*)out, member_idx, pe_idx, cmask, lprob, feat,
            pre_table, w1, b1, g1, bb1, norm_g, norm_b);
        gemm_inplace_kernel<<<dim3(98, 2), 256, 0, stream>>>(lin_w, lin_b, out);
    }
}